// Round 1
// baseline (3108.516 us; speedup 1.0000x reference)
//
#include <hip/hip_runtime.h>
#include <math.h>

#define NN   100000   // nodes
#define NE   1600000  // edges
#define IND  256      // input dim
#define HIDD 64       // hidden dim
#define OUTD 40       // output dim
#define COEF 0.1f     // 2*mu/p = 2*0.1/2.0

// ---------------------------------------------------------------- in-degree
__global__ void deg_kernel(const int* __restrict__ dst, int* __restrict__ indeg) {
    int e = blockIdx.x * blockDim.x + threadIdx.x;
    if (e < NE) atomicAdd(&indeg[dst[e]], 1);
}

// ------------------------------------------------- per-node dinv/alpha/beta
__global__ void node_kernel(const int* __restrict__ indeg,
                            float* __restrict__ dinv,
                            float* __restrict__ alpha,
                            float* __restrict__ beta) {
    int i = blockIdx.x * blockDim.x + threadIdx.x;
    if (i >= NN) return;
    int d = indeg[i];
    float deg = (d > 0) ? (float)d : 1.0f;
    dinv[i] = rsqrtf(deg);
    float denom = (float)d / deg + COEF;   // indeg/max(indeg,1) + coef
    float a = 1.0f / denom;
    alpha[i] = a;
    beta[i]  = COEF * a;
}

// ------------------------------------------- per-edge weight (iter-invariant)
__global__ void wp_kernel(const int* __restrict__ src, const int* __restrict__ dst,
                          const float* __restrict__ dinv, const float* __restrict__ alpha,
                          float* __restrict__ wp) {
    int e = blockIdx.x * blockDim.x + threadIdx.x;
    if (e >= NE) return;
    int s = src[e], d = dst[e];
    wp[e] = alpha[d] * dinv[s] * dinv[d];
}

// ------------------------------------------------- h = relu(x @ W1 + b1)
// block = 256 threads, each thread computes one full row (64 outputs).
// W1 staged in LDS in two K-chunks of 128 (32 KB each).
__global__ __launch_bounds__(256) void gemm1_kernel(const float* __restrict__ x,
                                                    const float* __restrict__ W1,
                                                    const float* __restrict__ b1,
                                                    float* __restrict__ h) {
    __shared__ float wlds[128 * HIDD];  // 32 KB
    int tid = threadIdx.x;
    int row = blockIdx.x * 256 + tid;

    float acc[HIDD];
#pragma unroll
    for (int j = 0; j < HIDD; j++) acc[j] = b1[j];

    const float4* x4 = (const float4*)(x + (size_t)row * IND);

    for (int c = 0; c < 2; c++) {
        __syncthreads();
        const float4* wg = (const float4*)(W1 + (size_t)c * 128 * HIDD);
        float4* wl = (float4*)wlds;
#pragma unroll
        for (int i = 0; i < 8; i++) wl[tid + i * 256] = wg[tid + i * 256];
        __syncthreads();

        if (row < NN) {
            for (int kk = 0; kk < 32; kk++) {
                float4 xv = x4[c * 32 + kk];
#pragma unroll
                for (int u = 0; u < 4; u++) {
                    float xs = (u == 0) ? xv.x : (u == 1) ? xv.y : (u == 2) ? xv.z : xv.w;
                    const float4* wrow = (const float4*)(wlds + (kk * 4 + u) * HIDD);
#pragma unroll
                    for (int j = 0; j < 16; j++) {
                        float4 wv = wrow[j];
                        acc[4 * j + 0] += xs * wv.x;
                        acc[4 * j + 1] += xs * wv.y;
                        acc[4 * j + 2] += xs * wv.z;
                        acc[4 * j + 3] += xs * wv.w;
                    }
                }
            }
        }
    }

    if (row < NN) {
        float4* hv = (float4*)(h + (size_t)row * HIDD);
#pragma unroll
        for (int j = 0; j < 16; j++) {
            float4 o;
            o.x = fmaxf(acc[4 * j + 0], 0.0f);
            o.y = fmaxf(acc[4 * j + 1], 0.0f);
            o.z = fmaxf(acc[4 * j + 2], 0.0f);
            o.w = fmaxf(acc[4 * j + 3], 0.0f);
            hv[j] = o;
        }
    }
}

// ------------------------------------------------- f_next = beta * h
__global__ void init_kernel(const float* __restrict__ h, const float* __restrict__ beta,
                            float* __restrict__ fn) {
    int t = blockIdx.x * blockDim.x + threadIdx.x;  // NN*16 float4 chunks
    if (t >= NN * 16) return;
    int i = t >> 4;
    float b = beta[i];
    float4 v = ((const float4*)h)[t];
    float4 o;
    o.x = b * v.x; o.y = b * v.y; o.z = b * v.z; o.w = b * v.w;
    ((float4*)fn)[t] = o;
}

// ------------------------------------------------- f_next[dst] += wp_e * f[src]
// 16 lanes per edge, each lane does one float4 gather + 4 f32 atomics.
__global__ void scatter_kernel(const int* __restrict__ src, const int* __restrict__ dst,
                               const float* __restrict__ wp,
                               const float* __restrict__ f, float* __restrict__ fn) {
    long long t = (long long)blockIdx.x * blockDim.x + threadIdx.x;
    int e = (int)(t >> 4);
    int c = (int)(t & 15);
    if (e >= NE) return;
    int s = src[e], d = dst[e];
    float w = wp[e];
    float4 v = ((const float4*)f)[(size_t)s * 16 + c];
    float* p = fn + (size_t)d * HIDD + c * 4;
    atomicAdd(p + 0, w * v.x);
    atomicAdd(p + 1, w * v.y);
    atomicAdd(p + 2, w * v.z);
    atomicAdd(p + 3, w * v.w);
}

// ------------------------------------------------- out = log_softmax(f @ W2 + b2)
// one wave per row; lane j (<40) holds output column j.
__global__ __launch_bounds__(256) void out_kernel(const float* __restrict__ f,
                                                  const float* __restrict__ W2,
                                                  const float* __restrict__ b2,
                                                  float* __restrict__ out) {
    __shared__ float w2l[HIDD * OUTD];  // 2560 floats
    __shared__ float b2l[OUTD];
    int tid = threadIdx.x;
    for (int i = tid; i < HIDD * OUTD; i += 256) w2l[i] = W2[i];
    if (tid < OUTD) b2l[tid] = b2[tid];
    __syncthreads();

    int wid = tid >> 6, lane = tid & 63;
    int row = blockIdx.x * 4 + wid;
    if (row >= NN) return;

    const float* fr = f + (size_t)row * HIDD;
    int col = (lane < OUTD) ? lane : 0;
    float acc = (lane < OUTD) ? b2l[col] : 0.0f;
#pragma unroll
    for (int k = 0; k < HIDD; k++) {
        acc += fr[k] * w2l[k * OUTD + col];
    }

    float v = (lane < OUTD) ? acc : -INFINITY;
#pragma unroll
    for (int off = 32; off; off >>= 1) v = fmaxf(v, __shfl_xor(v, off));
    float ex = (lane < OUTD) ? __expf(acc - v) : 0.0f;
    float s = ex;
#pragma unroll
    for (int off = 32; off; off >>= 1) s += __shfl_xor(s, off);
    if (lane < OUTD) out[(size_t)row * OUTD + lane] = acc - v - __logf(s);
}

// ----------------------------------------------------------------------------
static inline size_t align256(size_t x) { return (x + 255) & ~(size_t)255; }

extern "C" void kernel_launch(void* const* d_in, const int* in_sizes, int n_in,
                              void* d_out, int out_size, void* d_ws, size_t ws_size,
                              hipStream_t stream) {
    const float* x  = (const float*)d_in[0];
    const int*   ei = (const int*)d_in[1];
    const float* W1 = (const float*)d_in[2];
    const float* b1 = (const float*)d_in[3];
    const float* W2 = (const float*)d_in[4];
    const float* b2 = (const float*)d_in[5];
    float* out = (float*)d_out;

    const int* src = ei;        // edge_index[0]
    const int* dst = ei + NE;   // edge_index[1]

    char* ws = (char*)d_ws;
    size_t off = 0;
    int*   indeg = (int*)(ws + off);   off += align256((size_t)NN * 4);
    float* dinv  = (float*)(ws + off); off += align256((size_t)NN * 4);
    float* alpha = (float*)(ws + off); off += align256((size_t)NN * 4);
    float* beta  = (float*)(ws + off); off += align256((size_t)NN * 4);
    float* wp    = (float*)(ws + off); off += align256((size_t)NE * 4);
    float* h     = (float*)(ws + off); off += align256((size_t)NN * HIDD * 4);
    float* fa    = (float*)(ws + off); off += align256((size_t)NN * HIDD * 4);
    float* fb    = (float*)(ws + off); off += align256((size_t)NN * HIDD * 4);

    hipMemsetAsync(indeg, 0, (size_t)NN * 4, stream);

    deg_kernel<<<(NE + 255) / 256, 256, 0, stream>>>(dst, indeg);
    node_kernel<<<(NN + 255) / 256, 256, 0, stream>>>(indeg, dinv, alpha, beta);
    wp_kernel<<<(NE + 255) / 256, 256, 0, stream>>>(src, dst, dinv, alpha, wp);

    gemm1_kernel<<<(NN + 255) / 256, 256, 0, stream>>>(x, W1, b1, h);

    // iteration 1: fa = beta*h + A h
    init_kernel<<<(NN * 16 + 255) / 256, 256, 0, stream>>>(h, beta, fa);
    scatter_kernel<<<(int)(((long long)NE * 16 + 255) / 256), 256, 0, stream>>>(src, dst, wp, h, fa);

    // iteration 2: fb = beta*h + A fa
    init_kernel<<<(NN * 16 + 255) / 256, 256, 0, stream>>>(h, beta, fb);
    scatter_kernel<<<(int)(((long long)NE * 16 + 255) / 256), 256, 0, stream>>>(src, dst, wp, fa, fb);

    out_kernel<<<(NN + 3) / 4, 256, 0, stream>>>(fb, W2, b2, out);
}

// Round 2
// 622.074 us; speedup vs baseline: 4.9970x; 4.9970x over previous
//
#include <hip/hip_runtime.h>
#include <math.h>

#define NN   100000   // nodes
#define NE   1600000  // edges
#define IND  256      // input dim
#define HIDD 64       // hidden dim
#define OUTD 40       // output dim
#define COEF 0.1f     // 2*mu/p = 2*0.1/2.0

#define SCAN_CHUNK 1024
#define SCAN_BLKS  ((NN + SCAN_CHUNK - 1) / SCAN_CHUNK)   // 98

// ---------------------------------------------------------------- in-degree
__global__ void deg_kernel(const int* __restrict__ dst, int* __restrict__ indeg) {
    int e = blockIdx.x * blockDim.x + threadIdx.x;
    if (e < NE) atomicAdd(&indeg[dst[e]], 1);
}

// ------------------------------------------------- per-node dinv/alpha/beta
__global__ void node_kernel(const int* __restrict__ indeg,
                            float* __restrict__ dinv,
                            float* __restrict__ alpha,
                            float* __restrict__ beta) {
    int i = blockIdx.x * blockDim.x + threadIdx.x;
    if (i >= NN) return;
    int d = indeg[i];
    float deg = (d > 0) ? (float)d : 1.0f;
    dinv[i] = rsqrtf(deg);
    float denom = (float)d / deg + COEF;   // indeg/max(indeg,1) + coef
    float a = 1.0f / denom;
    alpha[i] = a;
    beta[i]  = COEF * a;
}

// ------------------------------------------------- scan stage A: block sums
__global__ __launch_bounds__(256) void scanA_kernel(const int* __restrict__ indeg,
                                                    int* __restrict__ blocksum) {
    __shared__ int lds[256];
    int b = blockIdx.x, t = threadIdx.x;
    int base = b * SCAN_CHUNK + t * 4;
    int s = 0;
#pragma unroll
    for (int j = 0; j < 4; j++) {
        int i = base + j;
        if (i < NN) s += indeg[i];
    }
    lds[t] = s;
    __syncthreads();
    for (int off = 128; off; off >>= 1) {
        if (t < off) lds[t] += lds[t + off];
        __syncthreads();
    }
    if (t == 0) blocksum[b] = lds[0];
}

// --------------------------------- scan stage B: exclusive scan of block sums
__global__ void scanB_kernel(int* __restrict__ blocksum, int* __restrict__ row_ptr) {
    if (threadIdx.x == 0 && blockIdx.x == 0) {
        int acc = 0;
        for (int i = 0; i < SCAN_BLKS; i++) {
            int v = blocksum[i];
            blocksum[i] = acc;
            acc += v;
        }
        row_ptr[NN] = acc;   // == NE
    }
}

// -------------------- scan stage C: per-element exclusive scan -> row_ptr, cursor
__global__ __launch_bounds__(256) void scanC_kernel(const int* __restrict__ indeg,
                                                    const int* __restrict__ blocksum,
                                                    int* __restrict__ row_ptr,
                                                    int* __restrict__ cursor) {
    __shared__ int lds[256];
    int b = blockIdx.x, t = threadIdx.x;
    int base = b * SCAN_CHUNK + t * 4;
    int v[4];
    int s = 0;
#pragma unroll
    for (int j = 0; j < 4; j++) {
        int i = base + j;
        v[j] = (i < NN) ? indeg[i] : 0;
        s += v[j];
    }
    lds[t] = s;
    __syncthreads();
    // Hillis-Steele inclusive scan over thread sums
    for (int off = 1; off < 256; off <<= 1) {
        int x = (t >= off) ? lds[t - off] : 0;
        __syncthreads();
        lds[t] += x;
        __syncthreads();
    }
    int excl = lds[t] - s + blocksum[b];
#pragma unroll
    for (int j = 0; j < 4; j++) {
        int i = base + j;
        if (i < NN) {
            row_ptr[i] = excl;
            cursor[i]  = excl;
            excl += v[j];
        }
    }
}

// -------------------------- counting-sort fill: src_sorted, wp_sorted (by dst)
__global__ void fill_kernel(const int* __restrict__ src, const int* __restrict__ dst,
                            const float* __restrict__ dinv, const float* __restrict__ alpha,
                            int* __restrict__ cursor,
                            int* __restrict__ src_sorted, float* __restrict__ wp_sorted) {
    int e = blockIdx.x * blockDim.x + threadIdx.x;
    if (e >= NE) return;
    int s = src[e], d = dst[e];
    int pos = atomicAdd(&cursor[d], 1);
    src_sorted[pos] = s;
    wp_sorted[pos]  = alpha[d] * dinv[s] * dinv[d];
}

// ------------------------------------------------- h = relu(x @ W1 + b1)
__global__ __launch_bounds__(256) void gemm1_kernel(const float* __restrict__ x,
                                                    const float* __restrict__ W1,
                                                    const float* __restrict__ b1,
                                                    float* __restrict__ h) {
    __shared__ float wlds[128 * HIDD];  // 32 KB
    int tid = threadIdx.x;
    int row = blockIdx.x * 256 + tid;

    float acc[HIDD];
#pragma unroll
    for (int j = 0; j < HIDD; j++) acc[j] = b1[j];

    const float4* x4 = (const float4*)(x + (size_t)row * IND);

    for (int c = 0; c < 2; c++) {
        __syncthreads();
        const float4* wg = (const float4*)(W1 + (size_t)c * 128 * HIDD);
        float4* wl = (float4*)wlds;
#pragma unroll
        for (int i = 0; i < 8; i++) wl[tid + i * 256] = wg[tid + i * 256];
        __syncthreads();

        if (row < NN) {
            for (int kk = 0; kk < 32; kk++) {
                float4 xv = x4[c * 32 + kk];
#pragma unroll
                for (int u = 0; u < 4; u++) {
                    float xs = (u == 0) ? xv.x : (u == 1) ? xv.y : (u == 2) ? xv.z : xv.w;
                    const float4* wrow = (const float4*)(wlds + (kk * 4 + u) * HIDD);
#pragma unroll
                    for (int j = 0; j < 16; j++) {
                        float4 wv = wrow[j];
                        acc[4 * j + 0] += xs * wv.x;
                        acc[4 * j + 1] += xs * wv.y;
                        acc[4 * j + 2] += xs * wv.z;
                        acc[4 * j + 3] += xs * wv.w;
                    }
                }
            }
        }
    }

    if (row < NN) {
        float4* hv = (float4*)(h + (size_t)row * HIDD);
#pragma unroll
        for (int j = 0; j < 16; j++) {
            float4 o;
            o.x = fmaxf(acc[4 * j + 0], 0.0f);
            o.y = fmaxf(acc[4 * j + 1], 0.0f);
            o.z = fmaxf(acc[4 * j + 2], 0.0f);
            o.w = fmaxf(acc[4 * j + 3], 0.0f);
            hv[j] = o;
        }
    }
}

// --------------- fn[i] = beta[i]*h[i] + sum_e wp_e * f[src_e]   (CSR gather)
// One wave per node. Lane layout: g = lane>>4 (edge subgroup 0..3),
// c = lane&15 (float4 chunk of the 64-dim feature). No atomics.
__global__ __launch_bounds__(256) void gather_kernel(const int* __restrict__ row_ptr,
                                                     const int* __restrict__ src_sorted,
                                                     const float* __restrict__ wp_sorted,
                                                     const float* __restrict__ f,
                                                     const float* __restrict__ h,
                                                     const float* __restrict__ beta,
                                                     float* __restrict__ fn) {
    int wid = threadIdx.x >> 6, lane = threadIdx.x & 63;
    int node = blockIdx.x * 4 + wid;
    if (node >= NN) return;
    int base = row_ptr[node];
    int end  = row_ptr[node + 1];
    int g = lane >> 4, c = lane & 15;

    float4 acc = make_float4(0.f, 0.f, 0.f, 0.f);
    for (int e = base + g; e < end; e += 4) {
        int s   = src_sorted[e];
        float w = wp_sorted[e];
        float4 v = ((const float4*)f)[(size_t)s * 16 + c];
        acc.x += w * v.x;
        acc.y += w * v.y;
        acc.z += w * v.z;
        acc.w += w * v.w;
    }
    // reduce across the 4 edge subgroups (lanes c, c+16, c+32, c+48)
    acc.x += __shfl_xor(acc.x, 16); acc.x += __shfl_xor(acc.x, 32);
    acc.y += __shfl_xor(acc.y, 16); acc.y += __shfl_xor(acc.y, 32);
    acc.z += __shfl_xor(acc.z, 16); acc.z += __shfl_xor(acc.z, 32);
    acc.w += __shfl_xor(acc.w, 16); acc.w += __shfl_xor(acc.w, 32);

    if (g == 0) {
        float b = beta[node];
        float4 hv = ((const float4*)h)[(size_t)node * 16 + c];
        float4 o;
        o.x = acc.x + b * hv.x;
        o.y = acc.y + b * hv.y;
        o.z = acc.z + b * hv.z;
        o.w = acc.w + b * hv.w;
        ((float4*)fn)[(size_t)node * 16 + c] = o;
    }
}

// ------------------------------------------------- out = log_softmax(f @ W2 + b2)
__global__ __launch_bounds__(256) void out_kernel(const float* __restrict__ f,
                                                  const float* __restrict__ W2,
                                                  const float* __restrict__ b2,
                                                  float* __restrict__ out) {
    __shared__ float w2l[HIDD * OUTD];
    __shared__ float b2l[OUTD];
    int tid = threadIdx.x;
    for (int i = tid; i < HIDD * OUTD; i += 256) w2l[i] = W2[i];
    if (tid < OUTD) b2l[tid] = b2[tid];
    __syncthreads();

    int wid = tid >> 6, lane = tid & 63;
    int row = blockIdx.x * 4 + wid;
    if (row >= NN) return;

    const float* fr = f + (size_t)row * HIDD;
    int col = (lane < OUTD) ? lane : 0;
    float acc = (lane < OUTD) ? b2l[col] : 0.0f;
#pragma unroll
    for (int k = 0; k < HIDD; k++) {
        acc += fr[k] * w2l[k * OUTD + col];
    }

    float v = (lane < OUTD) ? acc : -INFINITY;
#pragma unroll
    for (int off = 32; off; off >>= 1) v = fmaxf(v, __shfl_xor(v, off));
    float ex = (lane < OUTD) ? __expf(acc - v) : 0.0f;
    float s = ex;
#pragma unroll
    for (int off = 32; off; off >>= 1) s += __shfl_xor(s, off);
    if (lane < OUTD) out[(size_t)row * OUTD + lane] = acc - v - __logf(s);
}

// ----------------------------------------------------------------------------
static inline size_t align256(size_t x) { return (x + 255) & ~(size_t)255; }

extern "C" void kernel_launch(void* const* d_in, const int* in_sizes, int n_in,
                              void* d_out, int out_size, void* d_ws, size_t ws_size,
                              hipStream_t stream) {
    const float* x  = (const float*)d_in[0];
    const int*   ei = (const int*)d_in[1];
    const float* W1 = (const float*)d_in[2];
    const float* b1 = (const float*)d_in[3];
    const float* W2 = (const float*)d_in[4];
    const float* b2 = (const float*)d_in[5];
    float* out = (float*)d_out;

    const int* src = ei;        // edge_index[0]
    const int* dst = ei + NE;   // edge_index[1]

    char* ws = (char*)d_ws;
    size_t off = 0;
    int*   indeg    = (int*)(ws + off);   off += align256((size_t)NN * 4);
    float* dinv     = (float*)(ws + off); off += align256((size_t)NN * 4);
    float* alpha    = (float*)(ws + off); off += align256((size_t)NN * 4);
    float* beta     = (float*)(ws + off); off += align256((size_t)NN * 4);
    int*   row_ptr  = (int*)(ws + off);   off += align256((size_t)(NN + 1) * 4);
    int*   cursor   = (int*)(ws + off);   off += align256((size_t)NN * 4);
    int*   blocksum = (int*)(ws + off);   off += align256((size_t)SCAN_BLKS * 4);
    int*   src_sorted = (int*)(ws + off);   off += align256((size_t)NE * 4);
    float* wp_sorted  = (float*)(ws + off); off += align256((size_t)NE * 4);
    float* h  = (float*)(ws + off); off += align256((size_t)NN * HIDD * 4);
    float* fa = (float*)(ws + off); off += align256((size_t)NN * HIDD * 4);
    float* fb = (float*)(ws + off); off += align256((size_t)NN * HIDD * 4);

    hipMemsetAsync(indeg, 0, (size_t)NN * 4, stream);

    deg_kernel<<<(NE + 255) / 256, 256, 0, stream>>>(dst, indeg);
    node_kernel<<<(NN + 255) / 256, 256, 0, stream>>>(indeg, dinv, alpha, beta);

    // CSR build
    scanA_kernel<<<SCAN_BLKS, 256, 0, stream>>>(indeg, blocksum);
    scanB_kernel<<<1, 64, 0, stream>>>(blocksum, row_ptr);
    scanC_kernel<<<SCAN_BLKS, 256, 0, stream>>>(indeg, blocksum, row_ptr, cursor);
    fill_kernel<<<(NE + 255) / 256, 256, 0, stream>>>(src, dst, dinv, alpha, cursor,
                                                      src_sorted, wp_sorted);

    gemm1_kernel<<<(NN + 255) / 256, 256, 0, stream>>>(x, W1, b1, h);

    // iteration 1: fa = beta*h + A h
    gather_kernel<<<(NN + 3) / 4, 256, 0, stream>>>(row_ptr, src_sorted, wp_sorted,
                                                    h, h, beta, fa);
    // iteration 2: fb = beta*h + A fa
    gather_kernel<<<(NN + 3) / 4, 256, 0, stream>>>(row_ptr, src_sorted, wp_sorted,
                                                    fa, h, beta, fb);

    out_kernel<<<(NN + 3) / 4, 256, 0, stream>>>(fb, W2, b2, out);
}

// Round 3
// 618.934 us; speedup vs baseline: 5.0224x; 1.0051x over previous
//
#include <hip/hip_runtime.h>
#include <math.h>

#define NN   100000   // nodes
#define NE   1600000  // edges
#define IND  256      // input dim
#define HIDD 64       // hidden dim
#define OUTD 40       // output dim
#define COEF 0.1f     // 2*mu/p = 2*0.1/2.0

#define SCAN_CHUNK 1024
#define SCAN_BLKS  ((NN + SCAN_CHUNK - 1) / SCAN_CHUNK)   // 98

#define NPART   25        // dst>>12 -> 0..24
#define CHUNK_A 2048      // edges per partition-pass block
#define PBLKS   ((NE + CHUNK_A - 1) / CHUNK_A)            // 782

// ---------------------------------------------------------------- in-degree
__global__ void deg_kernel(const int* __restrict__ dst, int* __restrict__ indeg) {
    int e = blockIdx.x * blockDim.x + threadIdx.x;
    if (e < NE) atomicAdd(&indeg[dst[e]], 1);
}

// ------------------------------------- per-node dinv, adinv=alpha*dinv, beta
__global__ void node_kernel(const int* __restrict__ indeg,
                            float* __restrict__ dinv,
                            float* __restrict__ adinv,
                            float* __restrict__ beta) {
    int i = blockIdx.x * blockDim.x + threadIdx.x;
    if (i >= NN) return;
    int d = indeg[i];
    float deg = (d > 0) ? (float)d : 1.0f;
    float di = rsqrtf(deg);
    dinv[i] = di;
    float denom = (float)d / deg + COEF;   // indeg/max(indeg,1) + coef
    float a = 1.0f / denom;
    adinv[i] = a * di;
    beta[i]  = COEF * a;
}

// ------------------------------------------------- scan stage A: block sums
__global__ __launch_bounds__(256) void scanA_kernel(const int* __restrict__ indeg,
                                                    int* __restrict__ blocksum) {
    __shared__ int lds[256];
    int b = blockIdx.x, t = threadIdx.x;
    int base = b * SCAN_CHUNK + t * 4;
    int s = 0;
#pragma unroll
    for (int j = 0; j < 4; j++) {
        int i = base + j;
        if (i < NN) s += indeg[i];
    }
    lds[t] = s;
    __syncthreads();
    for (int off = 128; off; off >>= 1) {
        if (t < off) lds[t] += lds[t + off];
        __syncthreads();
    }
    if (t == 0) blocksum[b] = lds[0];
}

// --------------------------------- scan stage B: exclusive scan of block sums
__global__ void scanB_kernel(int* __restrict__ blocksum, int* __restrict__ row_ptr) {
    if (threadIdx.x == 0 && blockIdx.x == 0) {
        int acc = 0;
        for (int i = 0; i < SCAN_BLKS; i++) {
            int v = blocksum[i];
            blocksum[i] = acc;
            acc += v;
        }
        row_ptr[NN] = acc;   // == NE
    }
}

// -------------------- scan stage C: per-element exclusive scan -> row_ptr, cursor
__global__ __launch_bounds__(256) void scanC_kernel(const int* __restrict__ indeg,
                                                    const int* __restrict__ blocksum,
                                                    int* __restrict__ row_ptr,
                                                    int* __restrict__ cursor) {
    __shared__ int lds[256];
    int b = blockIdx.x, t = threadIdx.x;
    int base = b * SCAN_CHUNK + t * 4;
    int v[4];
    int s = 0;
#pragma unroll
    for (int j = 0; j < 4; j++) {
        int i = base + j;
        v[j] = (i < NN) ? indeg[i] : 0;
        s += v[j];
    }
    lds[t] = s;
    __syncthreads();
    for (int off = 1; off < 256; off <<= 1) {
        int x = (t >= off) ? lds[t - off] : 0;
        __syncthreads();
        lds[t] += x;
        __syncthreads();
    }
    int excl = lds[t] - s + blocksum[b];
#pragma unroll
    for (int j = 0; j < 4; j++) {
        int i = base + j;
        if (i < NN) {
            row_ptr[i] = excl;
            cursor[i]  = excl;
            excl += v[j];
        }
    }
}

// ------------------------ partition pass A1: per-partition edge counts (global)
__global__ __launch_bounds__(256) void pcount_kernel(const int* __restrict__ dst,
                                                     int* __restrict__ gcount) {
    __shared__ int cnt[NPART];
    int t = threadIdx.x;
    if (t < NPART) cnt[t] = 0;
    __syncthreads();
    int base = blockIdx.x * CHUNK_A;
    int end = base + CHUNK_A; if (end > NE) end = NE;
    for (int e = base + t; e < end; e += 256)
        atomicAdd(&cnt[dst[e] >> 12], 1);
    __syncthreads();
    if (t < NPART) atomicAdd(&gcount[t], cnt[t]);
}

// ------------------------ partition pass A2: scan of 25 partition counts
__global__ void pscan_kernel(const int* __restrict__ gcount,
                             int* __restrict__ gcursor) {
    if (threadIdx.x == 0 && blockIdx.x == 0) {
        int acc = 0;
        for (int p = 0; p < NPART; p++) {
            int v = gcount[p];
            gcursor[p] = acc;
            acc += v;
        }
    }
}

// --------------- partition pass A3: bin edges by dst partition into ep (int2)
__global__ __launch_bounds__(256) void pfill_kernel(const int* __restrict__ src,
                                                    const int* __restrict__ dst,
                                                    int* __restrict__ gcursor,
                                                    int2* __restrict__ ep) {
    __shared__ int cnt[NPART];
    __shared__ int basep[NPART];
    int t = threadIdx.x;
    if (t < NPART) cnt[t] = 0;
    __syncthreads();
    int base = blockIdx.x * CHUNK_A;
    int end = base + CHUNK_A; if (end > NE) end = NE;
    for (int e = base + t; e < end; e += 256)
        atomicAdd(&cnt[dst[e] >> 12], 1);
    __syncthreads();
    if (t < NPART) {
        basep[t] = atomicAdd(&gcursor[t], cnt[t]);
        cnt[t] = 0;
    }
    __syncthreads();
    for (int e = base + t; e < end; e += 256) {
        int d = dst[e];
        int p = d >> 12;
        int pos = basep[p] + atomicAdd(&cnt[p], 1);
        ep[pos] = make_int2(src[e], d);
    }
}

// --------------- pass B: scatter partition-ordered edges into CSR src_sorted
__global__ void fill2_kernel(const int2* __restrict__ ep,
                             int* __restrict__ cursor,
                             int* __restrict__ src_sorted) {
    int e = blockIdx.x * blockDim.x + threadIdx.x;
    if (e >= NE) return;
    int2 sd = ep[e];
    int pos = atomicAdd(&cursor[sd.y], 1);
    src_sorted[pos] = sd.x;
}

// ------------------------------------------------- h = relu(x @ W1 + b1)
__global__ __launch_bounds__(256) void gemm1_kernel(const float* __restrict__ x,
                                                    const float* __restrict__ W1,
                                                    const float* __restrict__ b1,
                                                    float* __restrict__ h) {
    __shared__ float wlds[128 * HIDD];  // 32 KB
    int tid = threadIdx.x;
    int row = blockIdx.x * 256 + tid;

    float acc[HIDD];
#pragma unroll
    for (int j = 0; j < HIDD; j++) acc[j] = b1[j];

    const float4* x4 = (const float4*)(x + (size_t)row * IND);

    for (int c = 0; c < 2; c++) {
        __syncthreads();
        const float4* wg = (const float4*)(W1 + (size_t)c * 128 * HIDD);
        float4* wl = (float4*)wlds;
#pragma unroll
        for (int i = 0; i < 8; i++) wl[tid + i * 256] = wg[tid + i * 256];
        __syncthreads();

        if (row < NN) {
            for (int kk = 0; kk < 32; kk++) {
                float4 xv = x4[c * 32 + kk];
#pragma unroll
                for (int u = 0; u < 4; u++) {
                    float xs = (u == 0) ? xv.x : (u == 1) ? xv.y : (u == 2) ? xv.z : xv.w;
                    const float4* wrow = (const float4*)(wlds + (kk * 4 + u) * HIDD);
#pragma unroll
                    for (int j = 0; j < 16; j++) {
                        float4 wv = wrow[j];
                        acc[4 * j + 0] += xs * wv.x;
                        acc[4 * j + 1] += xs * wv.y;
                        acc[4 * j + 2] += xs * wv.z;
                        acc[4 * j + 3] += xs * wv.w;
                    }
                }
            }
        }
    }

    if (row < NN) {
        float4* hv = (float4*)(h + (size_t)row * HIDD);
#pragma unroll
        for (int j = 0; j < 16; j++) {
            float4 o;
            o.x = fmaxf(acc[4 * j + 0], 0.0f);
            o.y = fmaxf(acc[4 * j + 1], 0.0f);
            o.z = fmaxf(acc[4 * j + 2], 0.0f);
            o.w = fmaxf(acc[4 * j + 3], 0.0f);
            hv[j] = o;
        }
    }
}

// --- fn[i] = beta[i]*h[i] + adinv[i] * sum_e dinv[src_e] * f[src_e]  (CSR gather)
__global__ __launch_bounds__(256) void gather_kernel(const int* __restrict__ row_ptr,
                                                     const int* __restrict__ src_sorted,
                                                     const float* __restrict__ dinv,
                                                     const float* __restrict__ adinv,
                                                     const float* __restrict__ f,
                                                     const float* __restrict__ h,
                                                     const float* __restrict__ beta,
                                                     float* __restrict__ fn) {
    int wid = threadIdx.x >> 6, lane = threadIdx.x & 63;
    int node = blockIdx.x * 4 + wid;
    if (node >= NN) return;
    int base = row_ptr[node];
    int end  = row_ptr[node + 1];
    int g = lane >> 4, c = lane & 15;

    float4 acc = make_float4(0.f, 0.f, 0.f, 0.f);
    for (int e = base + g; e < end; e += 4) {
        int s   = src_sorted[e];
        float w = dinv[s];
        float4 v = ((const float4*)f)[(size_t)s * 16 + c];
        acc.x += w * v.x;
        acc.y += w * v.y;
        acc.z += w * v.z;
        acc.w += w * v.w;
    }
    // reduce across the 4 edge subgroups (lanes c, c+16, c+32, c+48)
    acc.x += __shfl_xor(acc.x, 16); acc.x += __shfl_xor(acc.x, 32);
    acc.y += __shfl_xor(acc.y, 16); acc.y += __shfl_xor(acc.y, 32);
    acc.z += __shfl_xor(acc.z, 16); acc.z += __shfl_xor(acc.z, 32);
    acc.w += __shfl_xor(acc.w, 16); acc.w += __shfl_xor(acc.w, 32);

    if (g == 0) {
        float an = adinv[node];
        float b  = beta[node];
        float4 hv = ((const float4*)h)[(size_t)node * 16 + c];
        float4 o;
        o.x = an * acc.x + b * hv.x;
        o.y = an * acc.y + b * hv.y;
        o.z = an * acc.z + b * hv.z;
        o.w = an * acc.w + b * hv.w;
        ((float4*)fn)[(size_t)node * 16 + c] = o;
    }
}

// ------------------------------------------------- out = log_softmax(f @ W2 + b2)
__global__ __launch_bounds__(256) void out_kernel(const float* __restrict__ f,
                                                  const float* __restrict__ W2,
                                                  const float* __restrict__ b2,
                                                  float* __restrict__ out) {
    __shared__ float w2l[HIDD * OUTD];
    __shared__ float b2l[OUTD];
    int tid = threadIdx.x;
    for (int i = tid; i < HIDD * OUTD; i += 256) w2l[i] = W2[i];
    if (tid < OUTD) b2l[tid] = b2[tid];
    __syncthreads();

    int wid = tid >> 6, lane = tid & 63;
    int row = blockIdx.x * 4 + wid;
    if (row >= NN) return;

    const float* fr = f + (size_t)row * HIDD;
    int col = (lane < OUTD) ? lane : 0;
    float acc = (lane < OUTD) ? b2l[col] : 0.0f;
#pragma unroll
    for (int k = 0; k < HIDD; k++) {
        acc += fr[k] * w2l[k * OUTD + col];
    }

    float v = (lane < OUTD) ? acc : -INFINITY;
#pragma unroll
    for (int off = 32; off; off >>= 1) v = fmaxf(v, __shfl_xor(v, off));
    float ex = (lane < OUTD) ? __expf(acc - v) : 0.0f;
    float s = ex;
#pragma unroll
    for (int off = 32; off; off >>= 1) s += __shfl_xor(s, off);
    if (lane < OUTD) out[(size_t)row * OUTD + lane] = acc - v - __logf(s);
}

// ----------------------------------------------------------------------------
static inline size_t align256(size_t x) { return (x + 255) & ~(size_t)255; }

extern "C" void kernel_launch(void* const* d_in, const int* in_sizes, int n_in,
                              void* d_out, int out_size, void* d_ws, size_t ws_size,
                              hipStream_t stream) {
    const float* x  = (const float*)d_in[0];
    const int*   ei = (const int*)d_in[1];
    const float* W1 = (const float*)d_in[2];
    const float* b1 = (const float*)d_in[3];
    const float* W2 = (const float*)d_in[4];
    const float* b2 = (const float*)d_in[5];
    float* out = (float*)d_out;

    const int* src = ei;        // edge_index[0]
    const int* dst = ei + NE;   // edge_index[1]

    char* ws = (char*)d_ws;
    size_t off = 0;
    int*   indeg    = (int*)(ws + off);   off += align256((size_t)NN * 4);
    float* dinv     = (float*)(ws + off); off += align256((size_t)NN * 4);
    float* adinv    = (float*)(ws + off); off += align256((size_t)NN * 4);
    float* beta     = (float*)(ws + off); off += align256((size_t)NN * 4);
    int*   row_ptr  = (int*)(ws + off);   off += align256((size_t)(NN + 1) * 4);
    int*   cursor   = (int*)(ws + off);   off += align256((size_t)NN * 4);
    int*   blocksum = (int*)(ws + off);   off += align256((size_t)SCAN_BLKS * 4);
    int*   gcount   = (int*)(ws + off);   off += align256((size_t)NPART * 4);
    int*   gcursor  = (int*)(ws + off);   off += align256((size_t)NPART * 4);
    int*   src_sorted = (int*)(ws + off); off += align256((size_t)NE * 4);
    int2*  ep       = (int2*)(ws + off);  off += align256((size_t)NE * 8);
    float* h  = (float*)(ws + off); off += align256((size_t)NN * HIDD * 4);
    float* fa = (float*)(ws + off); off += align256((size_t)NN * HIDD * 4);
    float* fb = (float*)(ws + off); off += align256((size_t)NN * HIDD * 4);

    hipMemsetAsync(indeg, 0, (size_t)NN * 4, stream);
    hipMemsetAsync(gcount, 0, (size_t)NPART * 4, stream);

    deg_kernel<<<(NE + 255) / 256, 256, 0, stream>>>(dst, indeg);
    node_kernel<<<(NN + 255) / 256, 256, 0, stream>>>(indeg, dinv, adinv, beta);

    // CSR row pointers
    scanA_kernel<<<SCAN_BLKS, 256, 0, stream>>>(indeg, blocksum);
    scanB_kernel<<<1, 64, 0, stream>>>(blocksum, row_ptr);
    scanC_kernel<<<SCAN_BLKS, 256, 0, stream>>>(indeg, blocksum, row_ptr, cursor);

    // partition edges by dst>>12, then locality-friendly scatter into CSR
    pcount_kernel<<<PBLKS, 256, 0, stream>>>(dst, gcount);
    pscan_kernel<<<1, 64, 0, stream>>>(gcount, gcursor);
    pfill_kernel<<<PBLKS, 256, 0, stream>>>(src, dst, gcursor, ep);
    fill2_kernel<<<(NE + 255) / 256, 256, 0, stream>>>(ep, cursor, src_sorted);

    gemm1_kernel<<<(NN + 255) / 256, 256, 0, stream>>>(x, W1, b1, h);

    // iteration 1: fa = beta*h + A h
    gather_kernel<<<(NN + 3) / 4, 256, 0, stream>>>(row_ptr, src_sorted, dinv, adinv,
                                                    h, h, beta, fa);
    // iteration 2: fb = beta*h + A fa
    gather_kernel<<<(NN + 3) / 4, 256, 0, stream>>>(row_ptr, src_sorted, dinv, adinv,
                                                    fa, h, beta, fb);

    out_kernel<<<(NN + 3) / 4, 256, 0, stream>>>(fb, W2, b2, out);
}

// Round 4
// 536.449 us; speedup vs baseline: 5.7946x; 1.1538x over previous
//
#include <hip/hip_runtime.h>
#include <math.h>

#define NN   100000   // nodes
#define NE   1600000  // edges
#define IND  256      // input dim
#define HIDD 64       // hidden dim
#define OUTD 40       // output dim
#define COEF 0.1f     // 2*mu/p = 2*0.1/2.0

#define SCAN_CHUNK 1024
#define SCAN_BLKS  ((NN + SCAN_CHUNK - 1) / SCAN_CHUNK)   // 98

#define NPART   25        // dst>>12 -> 0..24
#define CHUNK_A 2048      // edges per partition-pass block
#define PBLKS   ((NE + CHUNK_A - 1) / CHUNK_A)            // 782

typedef __attribute__((ext_vector_type(8))) short frag8;   // 8 bf16
typedef __attribute__((ext_vector_type(4))) float f32x4;

__device__ __forceinline__ unsigned short f2bf(float x) {  // RNE
    unsigned u = __float_as_uint(x);
    u += 0x7fffu + ((u >> 16) & 1u);
    return (unsigned short)(u >> 16);
}
__device__ __forceinline__ float bflo(unsigned v) { return __uint_as_float(v << 16); }
__device__ __forceinline__ float bfhi(unsigned v) { return __uint_as_float(v & 0xffff0000u); }

// ---------------------------------------------------------------- in-degree
__global__ void deg_kernel(const int* __restrict__ dst, int* __restrict__ indeg) {
    int e = blockIdx.x * blockDim.x + threadIdx.x;
    if (e < NE) atomicAdd(&indeg[dst[e]], 1);
}

// ------------------------------------- per-node dinv, adinv=alpha*dinv, beta
__global__ void node_kernel(const int* __restrict__ indeg,
                            float* __restrict__ dinv,
                            float* __restrict__ adinv,
                            float* __restrict__ beta) {
    int i = blockIdx.x * blockDim.x + threadIdx.x;
    if (i >= NN) return;
    int d = indeg[i];
    float deg = (d > 0) ? (float)d : 1.0f;
    float di = rsqrtf(deg);
    dinv[i] = di;
    float denom = (float)d / deg + COEF;
    float a = 1.0f / denom;
    adinv[i] = a * di;
    beta[i]  = COEF * a;
}

// ------------------------------------------------- scan stage A: block sums
__global__ __launch_bounds__(256) void scanA_kernel(const int* __restrict__ indeg,
                                                    int* __restrict__ blocksum) {
    __shared__ int lds[256];
    int b = blockIdx.x, t = threadIdx.x;
    int base = b * SCAN_CHUNK + t * 4;
    int s = 0;
#pragma unroll
    for (int j = 0; j < 4; j++) {
        int i = base + j;
        if (i < NN) s += indeg[i];
    }
    lds[t] = s;
    __syncthreads();
    for (int off = 128; off; off >>= 1) {
        if (t < off) lds[t] += lds[t + off];
        __syncthreads();
    }
    if (t == 0) blocksum[b] = lds[0];
}

// --------------------------------- scan stage B: exclusive scan of block sums
__global__ void scanB_kernel(int* __restrict__ blocksum, int* __restrict__ row_ptr) {
    if (threadIdx.x == 0 && blockIdx.x == 0) {
        int acc = 0;
        for (int i = 0; i < SCAN_BLKS; i++) {
            int v = blocksum[i];
            blocksum[i] = acc;
            acc += v;
        }
        row_ptr[NN] = acc;   // == NE
    }
}

// -------------------- scan stage C: per-element exclusive scan -> row_ptr, cursor
__global__ __launch_bounds__(256) void scanC_kernel(const int* __restrict__ indeg,
                                                    const int* __restrict__ blocksum,
                                                    int* __restrict__ row_ptr,
                                                    int* __restrict__ cursor) {
    __shared__ int lds[256];
    int b = blockIdx.x, t = threadIdx.x;
    int base = b * SCAN_CHUNK + t * 4;
    int v[4];
    int s = 0;
#pragma unroll
    for (int j = 0; j < 4; j++) {
        int i = base + j;
        v[j] = (i < NN) ? indeg[i] : 0;
        s += v[j];
    }
    lds[t] = s;
    __syncthreads();
    for (int off = 1; off < 256; off <<= 1) {
        int x = (t >= off) ? lds[t - off] : 0;
        __syncthreads();
        lds[t] += x;
        __syncthreads();
    }
    int excl = lds[t] - s + blocksum[b];
#pragma unroll
    for (int j = 0; j < 4; j++) {
        int i = base + j;
        if (i < NN) {
            row_ptr[i] = excl;
            cursor[i]  = excl;
            excl += v[j];
        }
    }
}

// ------------------------ partition pass A1: per-partition edge counts (global)
__global__ __launch_bounds__(256) void pcount_kernel(const int* __restrict__ dst,
                                                     int* __restrict__ gcount) {
    __shared__ int cnt[NPART];
    int t = threadIdx.x;
    if (t < NPART) cnt[t] = 0;
    __syncthreads();
    int base = blockIdx.x * CHUNK_A;
    int end = base + CHUNK_A; if (end > NE) end = NE;
    for (int e = base + t; e < end; e += 256)
        atomicAdd(&cnt[dst[e] >> 12], 1);
    __syncthreads();
    if (t < NPART) atomicAdd(&gcount[t], cnt[t]);
}

// ------------------------ partition pass A2: scan of 25 partition counts
__global__ void pscan_kernel(const int* __restrict__ gcount,
                             int* __restrict__ gcursor) {
    if (threadIdx.x == 0 && blockIdx.x == 0) {
        int acc = 0;
        for (int p = 0; p < NPART; p++) {
            int v = gcount[p];
            gcursor[p] = acc;
            acc += v;
        }
    }
}

// --------------- partition pass A3: bin edges by dst partition into ep (int2)
__global__ __launch_bounds__(256) void pfill_kernel(const int* __restrict__ src,
                                                    const int* __restrict__ dst,
                                                    int* __restrict__ gcursor,
                                                    int2* __restrict__ ep) {
    __shared__ int cnt[NPART];
    __shared__ int basep[NPART];
    int t = threadIdx.x;
    if (t < NPART) cnt[t] = 0;
    __syncthreads();
    int base = blockIdx.x * CHUNK_A;
    int end = base + CHUNK_A; if (end > NE) end = NE;
    for (int e = base + t; e < end; e += 256)
        atomicAdd(&cnt[dst[e] >> 12], 1);
    __syncthreads();
    if (t < NPART) {
        basep[t] = atomicAdd(&gcursor[t], cnt[t]);
        cnt[t] = 0;
    }
    __syncthreads();
    for (int e = base + t; e < end; e += 256) {
        int d = dst[e];
        int p = d >> 12;
        int pos = basep[p] + atomicAdd(&cnt[p], 1);
        ep[pos] = make_int2(src[e], d);
    }
}

// --------------- pass B: scatter partition-ordered edges into CSR src_sorted
__global__ void fill2_kernel(const int2* __restrict__ ep,
                             int* __restrict__ cursor,
                             int* __restrict__ src_sorted) {
    int e = blockIdx.x * blockDim.x + threadIdx.x;
    if (e >= NE) return;
    int2 sd = ep[e];
    int pos = atomicAdd(&cursor[sd.y], 1);
    src_sorted[pos] = sd.x;
}

// ---------------------- h = relu(x @ W1 + b1), bf16 MFMA, bf16 output
// Block = 256 threads (4 waves), tile = 64 rows. W1^T staged in LDS (bf16,
// pad +8), x staged in two K=128 halves (bf16, pad +8). Each wave: 16 rows,
// 4 n-tiles of 16, mfma_f32_16x16x32_bf16.
#define XPAD 136   // 128+8 shorts; row stride 272 B (16B-aligned, 2-way conflicts only)
#define WPAD 264   // 256+8 shorts; row stride 528 B
__global__ __launch_bounds__(256) void gemm1_kernel(const float* __restrict__ x,
                                                    const float* __restrict__ W1,
                                                    const float* __restrict__ b1,
                                                    unsigned short* __restrict__ hb) {
    __shared__ short wt[64 * WPAD];   // 33792 B : wt[n][k] = W1[k][n]
    __shared__ short xa[64 * XPAD];   // 17408 B : xa[r][k-half]
    int tid = threadIdx.x;
    int block0 = blockIdx.x * 64;

    // stage W1 transposed as bf16 (64 KB fp32 read, L2-resident)
    for (int i = tid; i < IND * HIDD; i += 256) {
        int k = i >> 6, n = i & 63;
        wt[n * WPAD + k] = (short)f2bf(W1[i]);
    }

    const float4* x4 = (const float4*)(x + (size_t)block0 * IND);
    int wave = tid >> 6, lane = tid & 63;
    int m = lane & 15, q = lane >> 4;

    f32x4 acc[4] = {};

    for (int half = 0; half < 2; half++) {
        __syncthreads();
        // stage 64 x 128 fp32 -> bf16 (coalesced float4)
#pragma unroll
        for (int i = 0; i < 8; i++) {
            int f = i * 256 + tid;          // 0..2047 float4 within tile
            int row = f >> 5;               // 32 float4 per row-half
            int k4 = f & 31;
            int grow = block0 + row;
            float4 v = make_float4(0.f, 0.f, 0.f, 0.f);
            if (grow < NN) v = x4[row * 64 + half * 32 + k4];
            short4 sv;
            sv.x = (short)f2bf(v.x); sv.y = (short)f2bf(v.y);
            sv.z = (short)f2bf(v.z); sv.w = (short)f2bf(v.w);
            *(short4*)&xa[row * XPAD + k4 * 4] = sv;
        }
        __syncthreads();

        const short* arow = &xa[(wave * 16 + m) * XPAD + q * 8];
#pragma unroll
        for (int kt = 0; kt < 4; kt++) {
            frag8 a = *(const frag8*)(arow + kt * 32);
#pragma unroll
            for (int j = 0; j < 4; j++) {
                frag8 b = *(const frag8*)(&wt[(j * 16 + m) * WPAD + half * 128 + kt * 32 + q * 8]);
                acc[j] = __builtin_amdgcn_mfma_f32_16x16x32_bf16(a, b, acc[j], 0, 0, 0);
            }
        }
    }

    // epilogue: D row = q*4+r, col = m (within n-tile j)
#pragma unroll
    for (int j = 0; j < 4; j++) {
        int gcol = j * 16 + m;
        float bias = b1[gcol];
#pragma unroll
        for (int r = 0; r < 4; r++) {
            int grow = block0 + wave * 16 + q * 4 + r;
            if (grow < NN)
                hb[(size_t)grow * HIDD + gcol] = f2bf(fmaxf(acc[j][r] + bias, 0.0f));
        }
    }
}

// --- fn[i] = beta[i]*h[i] + adinv[i] * sum_e dinv[src_e] * f[src_e]  (bf16 CSR gather)
// One wave per node: g = lane>>3 (8 edge groups), c = lane&7 (16B chunk of 128B row).
__global__ __launch_bounds__(256) void gather_kernel(const int* __restrict__ row_ptr,
                                                     const int* __restrict__ src_sorted,
                                                     const float* __restrict__ dinv,
                                                     const float* __restrict__ adinv,
                                                     const unsigned short* __restrict__ fb,
                                                     const unsigned short* __restrict__ hb,
                                                     const float* __restrict__ beta,
                                                     unsigned short* __restrict__ fnb) {
    int wid = threadIdx.x >> 6, lane = threadIdx.x & 63;
    int node = blockIdx.x * 4 + wid;
    if (node >= NN) return;
    int base = row_ptr[node];
    int end  = row_ptr[node + 1];
    int g = lane >> 3, c = lane & 7;

    float acc[8];
#pragma unroll
    for (int i = 0; i < 8; i++) acc[i] = 0.f;

    for (int e = base + g; e < end; e += 8) {
        int s   = src_sorted[e];
        float w = dinv[s];
        uint4 v = ((const uint4*)fb)[(size_t)s * 8 + c];
        acc[0] += w * bflo(v.x); acc[1] += w * bfhi(v.x);
        acc[2] += w * bflo(v.y); acc[3] += w * bfhi(v.y);
        acc[4] += w * bflo(v.z); acc[5] += w * bfhi(v.z);
        acc[6] += w * bflo(v.w); acc[7] += w * bfhi(v.w);
    }
    // reduce across the 8 edge subgroups (xor 8,16,32)
#pragma unroll
    for (int i = 0; i < 8; i++) {
        acc[i] += __shfl_xor(acc[i], 8);
        acc[i] += __shfl_xor(acc[i], 16);
        acc[i] += __shfl_xor(acc[i], 32);
    }

    if (g == 0) {
        float an = adinv[node];
        float b  = beta[node];
        uint4 hv = ((const uint4*)hb)[(size_t)node * 8 + c];
        float o[8];
        o[0] = an * acc[0] + b * bflo(hv.x); o[1] = an * acc[1] + b * bfhi(hv.x);
        o[2] = an * acc[2] + b * bflo(hv.y); o[3] = an * acc[3] + b * bfhi(hv.y);
        o[4] = an * acc[4] + b * bflo(hv.z); o[5] = an * acc[5] + b * bfhi(hv.z);
        o[6] = an * acc[6] + b * bflo(hv.w); o[7] = an * acc[7] + b * bfhi(hv.w);
        uint4 r;
        r.x = (unsigned)f2bf(o[0]) | ((unsigned)f2bf(o[1]) << 16);
        r.y = (unsigned)f2bf(o[2]) | ((unsigned)f2bf(o[3]) << 16);
        r.z = (unsigned)f2bf(o[4]) | ((unsigned)f2bf(o[5]) << 16);
        r.w = (unsigned)f2bf(o[6]) | ((unsigned)f2bf(o[7]) << 16);
        ((uint4*)fnb)[(size_t)node * 8 + c] = r;
    }
}

// ------------------------------------------------- out = log_softmax(f @ W2 + b2)
__global__ __launch_bounds__(256) void out_kernel(const unsigned short* __restrict__ fb,
                                                  const float* __restrict__ W2,
                                                  const float* __restrict__ b2,
                                                  float* __restrict__ out) {
    __shared__ float w2l[HIDD * OUTD];
    __shared__ float b2l[OUTD];
    int tid = threadIdx.x;
    for (int i = tid; i < HIDD * OUTD; i += 256) w2l[i] = W2[i];
    if (tid < OUTD) b2l[tid] = b2[tid];
    __syncthreads();

    int wid = tid >> 6, lane = tid & 63;
    int row = blockIdx.x * 4 + wid;
    if (row >= NN) return;

    const unsigned short* fr = fb + (size_t)row * HIDD;
    int col = (lane < OUTD) ? lane : 0;
    float acc = (lane < OUTD) ? b2l[col] : 0.0f;
#pragma unroll
    for (int k = 0; k < HIDD; k++) {
        float fk = bflo((unsigned)fr[k]);
        acc += fk * w2l[k * OUTD + col];
    }

    float v = (lane < OUTD) ? acc : -INFINITY;
#pragma unroll
    for (int off = 32; off; off >>= 1) v = fmaxf(v, __shfl_xor(v, off));
    float ex = (lane < OUTD) ? __expf(acc - v) : 0.0f;
    float s = ex;
#pragma unroll
    for (int off = 32; off; off >>= 1) s += __shfl_xor(s, off);
    if (lane < OUTD) out[(size_t)row * OUTD + lane] = acc - v - __logf(s);
}

// ----------------------------------------------------------------------------
static inline size_t align256(size_t x) { return (x + 255) & ~(size_t)255; }

extern "C" void kernel_launch(void* const* d_in, const int* in_sizes, int n_in,
                              void* d_out, int out_size, void* d_ws, size_t ws_size,
                              hipStream_t stream) {
    const float* x  = (const float*)d_in[0];
    const int*   ei = (const int*)d_in[1];
    const float* W1 = (const float*)d_in[2];
    const float* b1 = (const float*)d_in[3];
    const float* W2 = (const float*)d_in[4];
    const float* b2 = (const float*)d_in[5];
    float* out = (float*)d_out;

    const int* src = ei;        // edge_index[0]
    const int* dst = ei + NE;   // edge_index[1]

    char* ws = (char*)d_ws;
    size_t off = 0;
    int*   indeg    = (int*)(ws + off);   off += align256((size_t)NN * 4);
    float* dinv     = (float*)(ws + off); off += align256((size_t)NN * 4);
    float* adinv    = (float*)(ws + off); off += align256((size_t)NN * 4);
    float* beta     = (float*)(ws + off); off += align256((size_t)NN * 4);
    int*   row_ptr  = (int*)(ws + off);   off += align256((size_t)(NN + 1) * 4);
    int*   cursor   = (int*)(ws + off);   off += align256((size_t)NN * 4);
    int*   blocksum = (int*)(ws + off);   off += align256((size_t)SCAN_BLKS * 4);
    int*   gcount   = (int*)(ws + off);   off += align256((size_t)NPART * 4);
    int*   gcursor  = (int*)(ws + off);   off += align256((size_t)NPART * 4);
    int*   src_sorted = (int*)(ws + off); off += align256((size_t)NE * 4);
    int2*  ep       = (int2*)(ws + off);  off += align256((size_t)NE * 8);
    unsigned short* hb = (unsigned short*)(ws + off); off += align256((size_t)NN * HIDD * 2);
    unsigned short* fa = (unsigned short*)(ws + off); off += align256((size_t)NN * HIDD * 2);
    unsigned short* fb = (unsigned short*)(ws + off); off += align256((size_t)NN * HIDD * 2);

    hipMemsetAsync(indeg, 0, (size_t)NN * 4, stream);
    hipMemsetAsync(gcount, 0, (size_t)NPART * 4, stream);

    deg_kernel<<<(NE + 255) / 256, 256, 0, stream>>>(dst, indeg);
    node_kernel<<<(NN + 255) / 256, 256, 0, stream>>>(indeg, dinv, adinv, beta);

    // CSR row pointers
    scanA_kernel<<<SCAN_BLKS, 256, 0, stream>>>(indeg, blocksum);
    scanB_kernel<<<1, 64, 0, stream>>>(blocksum, row_ptr);
    scanC_kernel<<<SCAN_BLKS, 256, 0, stream>>>(indeg, blocksum, row_ptr, cursor);

    // partition edges by dst>>12, then locality-friendly scatter into CSR
    pcount_kernel<<<PBLKS, 256, 0, stream>>>(dst, gcount);
    pscan_kernel<<<1, 64, 0, stream>>>(gcount, gcursor);
    pfill_kernel<<<PBLKS, 256, 0, stream>>>(src, dst, gcursor, ep);
    fill2_kernel<<<(NE + 255) / 256, 256, 0, stream>>>(ep, cursor, src_sorted);

    gemm1_kernel<<<(NN + 63) / 64, 256, 0, stream>>>(x, W1, b1, hb);

    // iteration 1: fa = beta*h + A h
    gather_kernel<<<(NN + 3) / 4, 256, 0, stream>>>(row_ptr, src_sorted, dinv, adinv,
                                                    hb, hb, beta, fa);
    // iteration 2: fb = beta*h + A fa
    gather_kernel<<<(NN + 3) / 4, 256, 0, stream>>>(row_ptr, src_sorted, dinv, adinv,
                                                    fa, hb, beta, fb);

    out_kernel<<<(NN + 3) / 4, 256, 0, stream>>>(fb, W2, b2, out);
}

// Round 5
// 487.136 us; speedup vs baseline: 6.3812x; 1.1012x over previous
//
#include <hip/hip_runtime.h>
#include <math.h>

#define NN   100000   // nodes
#define NE   1600000  // edges
#define IND  256      // input dim
#define HIDD 64       // hidden dim
#define OUTD 40       // output dim
#define COEF 0.1f     // 2*mu/p = 2*0.1/2.0

#define SCAN_CHUNK 1024
#define SCAN_BLKS  ((NN + SCAN_CHUNK - 1) / SCAN_CHUNK)   // 98

#define NPART   25        // dst>>12 -> 0..24
#define CHUNK_A 2048      // edges per partition-pass block
#define PBLKS   ((NE + CHUNK_A - 1) / CHUNK_A)            // 782

typedef __attribute__((ext_vector_type(8))) short frag8;   // 8 bf16
typedef __attribute__((ext_vector_type(4))) float f32x4;

__device__ __forceinline__ unsigned short f2bf(float x) {  // RNE
    unsigned u = __float_as_uint(x);
    u += 0x7fffu + ((u >> 16) & 1u);
    return (unsigned short)(u >> 16);
}
__device__ __forceinline__ float bflo(unsigned v) { return __uint_as_float(v << 16); }
__device__ __forceinline__ float bfhi(unsigned v) { return __uint_as_float(v & 0xffff0000u); }

// ---------------------------------------------------------------- in-degree
__global__ void deg_kernel(const int* __restrict__ dst, int* __restrict__ indeg) {
    int e = blockIdx.x * blockDim.x + threadIdx.x;
    if (e < NE) atomicAdd(&indeg[dst[e]], 1);
}

// ------------------------------------- per-node dinv, adinv=alpha*dinv, beta
__global__ void node_kernel(const int* __restrict__ indeg,
                            float* __restrict__ dinv,
                            float* __restrict__ adinv,
                            float* __restrict__ beta) {
    int i = blockIdx.x * blockDim.x + threadIdx.x;
    if (i >= NN) return;
    int d = indeg[i];
    float deg = (d > 0) ? (float)d : 1.0f;
    float di = rsqrtf(deg);
    dinv[i] = di;
    float denom = (float)d / deg + COEF;
    float a = 1.0f / denom;
    adinv[i] = a * di;
    beta[i]  = COEF * a;
}

// ------------------------------------------------- scan stage A: block sums
__global__ __launch_bounds__(256) void scanA_kernel(const int* __restrict__ indeg,
                                                    int* __restrict__ blocksum) {
    __shared__ int lds[256];
    int b = blockIdx.x, t = threadIdx.x;
    int base = b * SCAN_CHUNK + t * 4;
    int s = 0;
#pragma unroll
    for (int j = 0; j < 4; j++) {
        int i = base + j;
        if (i < NN) s += indeg[i];
    }
    lds[t] = s;
    __syncthreads();
    for (int off = 128; off; off >>= 1) {
        if (t < off) lds[t] += lds[t + off];
        __syncthreads();
    }
    if (t == 0) blocksum[b] = lds[0];
}

// --------------------------------- scan stage B: exclusive scan of block sums
__global__ void scanB_kernel(int* __restrict__ blocksum, int* __restrict__ row_ptr) {
    if (threadIdx.x == 0 && blockIdx.x == 0) {
        int acc = 0;
        for (int i = 0; i < SCAN_BLKS; i++) {
            int v = blocksum[i];
            blocksum[i] = acc;
            acc += v;
        }
        row_ptr[NN] = acc;   // == NE
    }
}

// -------------------- scan stage C: per-element exclusive scan -> row_ptr, cursor
__global__ __launch_bounds__(256) void scanC_kernel(const int* __restrict__ indeg,
                                                    const int* __restrict__ blocksum,
                                                    int* __restrict__ row_ptr,
                                                    int* __restrict__ cursor) {
    __shared__ int lds[256];
    int b = blockIdx.x, t = threadIdx.x;
    int base = b * SCAN_CHUNK + t * 4;
    int v[4];
    int s = 0;
#pragma unroll
    for (int j = 0; j < 4; j++) {
        int i = base + j;
        v[j] = (i < NN) ? indeg[i] : 0;
        s += v[j];
    }
    lds[t] = s;
    __syncthreads();
    for (int off = 1; off < 256; off <<= 1) {
        int x = (t >= off) ? lds[t - off] : 0;
        __syncthreads();
        lds[t] += x;
        __syncthreads();
    }
    int excl = lds[t] - s + blocksum[b];
#pragma unroll
    for (int j = 0; j < 4; j++) {
        int i = base + j;
        if (i < NN) {
            row_ptr[i] = excl;
            cursor[i]  = excl;
            excl += v[j];
        }
    }
}

// ------------------------ partition pass A1: per-partition edge counts (global)
__global__ __launch_bounds__(256) void pcount_kernel(const int* __restrict__ dst,
                                                     int* __restrict__ gcount) {
    __shared__ int cnt[NPART];
    int t = threadIdx.x;
    if (t < NPART) cnt[t] = 0;
    __syncthreads();
    int base = blockIdx.x * CHUNK_A;
    int end = base + CHUNK_A; if (end > NE) end = NE;
    for (int e = base + t; e < end; e += 256)
        atomicAdd(&cnt[dst[e] >> 12], 1);
    __syncthreads();
    if (t < NPART) atomicAdd(&gcount[t], cnt[t]);
}

// ------------------------ partition pass A2: scan of 25 partition counts
__global__ void pscan_kernel(const int* __restrict__ gcount,
                             int* __restrict__ gcursor) {
    if (threadIdx.x == 0 && blockIdx.x == 0) {
        int acc = 0;
        for (int p = 0; p < NPART; p++) {
            int v = gcount[p];
            gcursor[p] = acc;
            acc += v;
        }
    }
}

// --------------- partition pass A3: bin edges by dst partition into ep (int2)
__global__ __launch_bounds__(256) void pfill_kernel(const int* __restrict__ src,
                                                    const int* __restrict__ dst,
                                                    int* __restrict__ gcursor,
                                                    int2* __restrict__ ep) {
    __shared__ int cnt[NPART];
    __shared__ int basep[NPART];
    int t = threadIdx.x;
    if (t < NPART) cnt[t] = 0;
    __syncthreads();
    int base = blockIdx.x * CHUNK_A;
    int end = base + CHUNK_A; if (end > NE) end = NE;
    for (int e = base + t; e < end; e += 256)
        atomicAdd(&cnt[dst[e] >> 12], 1);
    __syncthreads();
    if (t < NPART) {
        basep[t] = atomicAdd(&gcursor[t], cnt[t]);
        cnt[t] = 0;
    }
    __syncthreads();
    for (int e = base + t; e < end; e += 256) {
        int d = dst[e];
        int p = d >> 12;
        int pos = basep[p] + atomicAdd(&cnt[p], 1);
        ep[pos] = make_int2(src[e], d);
    }
}

// --------------- pass B: scatter partition-ordered edges into CSR src_sorted
__global__ void fill2_kernel(const int2* __restrict__ ep,
                             int* __restrict__ cursor,
                             int* __restrict__ src_sorted) {
    int e = blockIdx.x * blockDim.x + threadIdx.x;
    if (e >= NE) return;
    int2 sd = ep[e];
    int pos = atomicAdd(&cursor[sd.y], 1);
    src_sorted[pos] = sd.x;
}

// ---------------------- h = relu(x @ W1 + b1), bf16 MFMA, bf16 output
#define XPAD 136   // 128+8 shorts
#define WPAD 264   // 256+8 shorts
__global__ __launch_bounds__(256) void gemm1_kernel(const float* __restrict__ x,
                                                    const float* __restrict__ W1,
                                                    const float* __restrict__ b1,
                                                    unsigned short* __restrict__ hb) {
    __shared__ short wt[64 * WPAD];   // wt[n][k] = W1[k][n]
    __shared__ short xa[64 * XPAD];   // xa[r][k-half]
    int tid = threadIdx.x;
    int block0 = blockIdx.x * 64;

    for (int i = tid; i < IND * HIDD; i += 256) {
        int k = i >> 6, n = i & 63;
        wt[n * WPAD + k] = (short)f2bf(W1[i]);
    }

    const float4* x4 = (const float4*)(x + (size_t)block0 * IND);
    int wave = tid >> 6, lane = tid & 63;
    int m = lane & 15, q = lane >> 4;

    f32x4 acc[4] = {};

    for (int half = 0; half < 2; half++) {
        __syncthreads();
#pragma unroll
        for (int i = 0; i < 8; i++) {
            int f = i * 256 + tid;
            int row = f >> 5;
            int k4 = f & 31;
            int grow = block0 + row;
            float4 v = make_float4(0.f, 0.f, 0.f, 0.f);
            if (grow < NN) v = x4[row * 64 + half * 32 + k4];
            short4 sv;
            sv.x = (short)f2bf(v.x); sv.y = (short)f2bf(v.y);
            sv.z = (short)f2bf(v.z); sv.w = (short)f2bf(v.w);
            *(short4*)&xa[row * XPAD + k4 * 4] = sv;
        }
        __syncthreads();

        const short* arow = &xa[(wave * 16 + m) * XPAD + q * 8];
#pragma unroll
        for (int kt = 0; kt < 4; kt++) {
            frag8 a = *(const frag8*)(arow + kt * 32);
#pragma unroll
            for (int j = 0; j < 4; j++) {
                frag8 b = *(const frag8*)(&wt[(j * 16 + m) * WPAD + half * 128 + kt * 32 + q * 8]);
                acc[j] = __builtin_amdgcn_mfma_f32_16x16x32_bf16(a, b, acc[j], 0, 0, 0);
            }
        }
    }

#pragma unroll
    for (int j = 0; j < 4; j++) {
        int gcol = j * 16 + m;
        float bias = b1[gcol];
#pragma unroll
        for (int r = 0; r < 4; r++) {
            int grow = block0 + wave * 16 + q * 4 + r;
            if (grow < NN)
                hb[(size_t)grow * HIDD + gcol] = f2bf(fmaxf(acc[j][r] + bias, 0.0f));
        }
    }
}

// --- fn[i] = beta[i]*h[i] + adinv[i] * sum_e dinv[src_e] * f[src_e]  (bf16 CSR gather)
__global__ __launch_bounds__(256) void gather_kernel(const int* __restrict__ row_ptr,
                                                     const int* __restrict__ src_sorted,
                                                     const float* __restrict__ dinv,
                                                     const float* __restrict__ adinv,
                                                     const unsigned short* __restrict__ fb,
                                                     const unsigned short* __restrict__ hb,
                                                     const float* __restrict__ beta,
                                                     unsigned short* __restrict__ fnb) {
    int wid = threadIdx.x >> 6, lane = threadIdx.x & 63;
    int node = blockIdx.x * 4 + wid;
    if (node >= NN) return;
    int base = row_ptr[node];
    int end  = row_ptr[node + 1];
    int g = lane >> 3, c = lane & 7;

    float acc[8];
#pragma unroll
    for (int i = 0; i < 8; i++) acc[i] = 0.f;

    for (int e = base + g; e < end; e += 8) {
        int s   = src_sorted[e];
        float w = dinv[s];
        uint4 v = ((const uint4*)fb)[(size_t)s * 8 + c];
        acc[0] += w * bflo(v.x); acc[1] += w * bfhi(v.x);
        acc[2] += w * bflo(v.y); acc[3] += w * bfhi(v.y);
        acc[4] += w * bflo(v.z); acc[5] += w * bfhi(v.z);
        acc[6] += w * bflo(v.w); acc[7] += w * bfhi(v.w);
    }
#pragma unroll
    for (int i = 0; i < 8; i++) {
        acc[i] += __shfl_xor(acc[i], 8);
        acc[i] += __shfl_xor(acc[i], 16);
        acc[i] += __shfl_xor(acc[i], 32);
    }

    if (g == 0) {
        float an = adinv[node];
        float b  = beta[node];
        uint4 hv = ((const uint4*)hb)[(size_t)node * 8 + c];
        float o[8];
        o[0] = an * acc[0] + b * bflo(hv.x); o[1] = an * acc[1] + b * bfhi(hv.x);
        o[2] = an * acc[2] + b * bflo(hv.y); o[3] = an * acc[3] + b * bfhi(hv.y);
        o[4] = an * acc[4] + b * bflo(hv.z); o[5] = an * acc[5] + b * bfhi(hv.z);
        o[6] = an * acc[6] + b * bflo(hv.w); o[7] = an * acc[7] + b * bfhi(hv.w);
        uint4 r;
        r.x = (unsigned)f2bf(o[0]) | ((unsigned)f2bf(o[1]) << 16);
        r.y = (unsigned)f2bf(o[2]) | ((unsigned)f2bf(o[3]) << 16);
        r.z = (unsigned)f2bf(o[4]) | ((unsigned)f2bf(o[5]) << 16);
        r.w = (unsigned)f2bf(o[6]) | ((unsigned)f2bf(o[7]) << 16);
        ((uint4*)fnb)[(size_t)node * 8 + c] = r;
    }
}

// ------------------- out = log_softmax(f @ W2 + b2), bf16 MFMA
// Block = 256 threads (4 waves) covers 256 rows; each wave does 4 row-tiles
// of 16. W2 padded to 48 cols -> 3 n-tiles x 2 k-steps of 16x16x32 MFMA.
// B-fragments built once into registers; A loaded straight from global fb.
// log_softmax in C-layout: row=q*4+r across the 16 m-lanes (shfl_xor 1/2/4/8).
__global__ __launch_bounds__(256) void out_kernel(const unsigned short* __restrict__ fb,
                                                  const float* __restrict__ W2,
                                                  const float* __restrict__ b2,
                                                  float* __restrict__ out) {
    __shared__ float w2l[HIDD * OUTD];   // raw W2, 10 KB
    int tid = threadIdx.x;
    for (int i = tid; i < HIDD * OUTD; i += 256) w2l[i] = W2[i];
    __syncthreads();

    int wave = tid >> 6, lane = tid & 63;
    int m = lane & 15, q = lane >> 4;

    // build 6 B-fragments in registers: bfr[j][s] = W2[k= s*32+q*8 .. +8][n= j*16+m]
    frag8 bfr[3][2];
    float bias[3];
#pragma unroll
    for (int j = 0; j < 3; j++) {
        int n = j * 16 + m;
        bias[j] = (n < OUTD) ? b2[n] : 0.0f;
#pragma unroll
        for (int s = 0; s < 2; s++) {
            short tmp[8];
#pragma unroll
            for (int i = 0; i < 8; i++) {
                int k = s * 32 + q * 8 + i;
                float w = (n < OUTD) ? w2l[k * OUTD + n] : 0.0f;
                tmp[i] = (short)f2bf(w);
            }
            bfr[j][s] = *(frag8*)tmp;
        }
    }

    int block0 = blockIdx.x * 256;
    for (int t = 0; t < 4; t++) {
        int row0 = block0 + wave * 64 + t * 16;
        if (row0 >= NN) break;
        int arow = row0 + m;
        if (arow >= NN) arow = NN - 1;           // clamp; garbage rows masked at store
        const frag8* ap = (const frag8*)(fb + (size_t)arow * HIDD);
        frag8 a0 = ap[q];                         // k = q*8
        frag8 a1 = ap[4 + q];                     // k = 32 + q*8

        f32x4 acc[3] = {};
#pragma unroll
        for (int j = 0; j < 3; j++) {
            acc[j] = __builtin_amdgcn_mfma_f32_16x16x32_bf16(a0, bfr[j][0], acc[j], 0, 0, 0);
            acc[j] = __builtin_amdgcn_mfma_f32_16x16x32_bf16(a1, bfr[j][1], acc[j], 0, 0, 0);
        }

#pragma unroll
        for (int r = 0; r < 4; r++) {
            int orow = row0 + q * 4 + r;
            float v0 = acc[0][r] + bias[0];
            float v1 = acc[1][r] + bias[1];
            float v2 = (m < 8) ? (acc[2][r] + bias[2]) : -INFINITY;
            float mx = fmaxf(fmaxf(v0, v1), v2);
            mx = fmaxf(mx, __shfl_xor(mx, 1));
            mx = fmaxf(mx, __shfl_xor(mx, 2));
            mx = fmaxf(mx, __shfl_xor(mx, 4));
            mx = fmaxf(mx, __shfl_xor(mx, 8));
            float sum = __expf(v0 - mx) + __expf(v1 - mx) + ((m < 8) ? __expf(v2 - mx) : 0.0f);
            sum += __shfl_xor(sum, 1);
            sum += __shfl_xor(sum, 2);
            sum += __shfl_xor(sum, 4);
            sum += __shfl_xor(sum, 8);
            float ls = mx + __logf(sum);
            if (orow < NN) {
                float* orow_p = out + (size_t)orow * OUTD;
                orow_p[m]      = v0 - ls;
                orow_p[16 + m] = v1 - ls;
                if (m < 8) orow_p[32 + m] = v2 - ls;
            }
        }
    }
}

// ----------------------------------------------------------------------------
static inline size_t align256(size_t x) { return (x + 255) & ~(size_t)255; }

extern "C" void kernel_launch(void* const* d_in, const int* in_sizes, int n_in,
                              void* d_out, int out_size, void* d_ws, size_t ws_size,
                              hipStream_t stream) {
    const float* x  = (const float*)d_in[0];
    const int*   ei = (const int*)d_in[1];
    const float* W1 = (const float*)d_in[2];
    const float* b1 = (const float*)d_in[3];
    const float* W2 = (const float*)d_in[4];
    const float* b2 = (const float*)d_in[5];
    float* out = (float*)d_out;

    const int* src = ei;        // edge_index[0]
    const int* dst = ei + NE;   // edge_index[1]

    char* ws = (char*)d_ws;
    size_t off = 0;
    int*   indeg    = (int*)(ws + off);   off += align256((size_t)NN * 4);
    float* dinv     = (float*)(ws + off); off += align256((size_t)NN * 4);
    float* adinv    = (float*)(ws + off); off += align256((size_t)NN * 4);
    float* beta     = (float*)(ws + off); off += align256((size_t)NN * 4);
    int*   row_ptr  = (int*)(ws + off);   off += align256((size_t)(NN + 1) * 4);
    int*   cursor   = (int*)(ws + off);   off += align256((size_t)NN * 4);
    int*   blocksum = (int*)(ws + off);   off += align256((size_t)SCAN_BLKS * 4);
    int*   gcount   = (int*)(ws + off);   off += align256((size_t)NPART * 4);
    int*   gcursor  = (int*)(ws + off);   off += align256((size_t)NPART * 4);
    int*   src_sorted = (int*)(ws + off); off += align256((size_t)NE * 4);
    int2*  ep       = (int2*)(ws + off);  off += align256((size_t)NE * 8);
    unsigned short* hb = (unsigned short*)(ws + off); off += align256((size_t)NN * HIDD * 2);
    unsigned short* fa = (unsigned short*)(ws + off); off += align256((size_t)NN * HIDD * 2);
    unsigned short* fb = (unsigned short*)(ws + off); off += align256((size_t)NN * HIDD * 2);

    hipMemsetAsync(indeg, 0, (size_t)NN * 4, stream);
    hipMemsetAsync(gcount, 0, (size_t)NPART * 4, stream);

    deg_kernel<<<(NE + 255) / 256, 256, 0, stream>>>(dst, indeg);
    node_kernel<<<(NN + 255) / 256, 256, 0, stream>>>(indeg, dinv, adinv, beta);

    // CSR row pointers
    scanA_kernel<<<SCAN_BLKS, 256, 0, stream>>>(indeg, blocksum);
    scanB_kernel<<<1, 64, 0, stream>>>(blocksum, row_ptr);
    scanC_kernel<<<SCAN_BLKS, 256, 0, stream>>>(indeg, blocksum, row_ptr, cursor);

    // partition edges by dst>>12, then locality-friendly scatter into CSR
    pcount_kernel<<<PBLKS, 256, 0, stream>>>(dst, gcount);
    pscan_kernel<<<1, 64, 0, stream>>>(gcount, gcursor);
    pfill_kernel<<<PBLKS, 256, 0, stream>>>(src, dst, gcursor, ep);
    fill2_kernel<<<(NE + 255) / 256, 256, 0, stream>>>(ep, cursor, src_sorted);

    gemm1_kernel<<<(NN + 63) / 64, 256, 0, stream>>>(x, W1, b1, hb);

    // iteration 1: fa = beta*h + A h
    gather_kernel<<<(NN + 3) / 4, 256, 0, stream>>>(row_ptr, src_sorted, dinv, adinv,
                                                    hb, hb, beta, fa);
    // iteration 2: fb = beta*h + A fa
    gather_kernel<<<(NN + 3) / 4, 256, 0, stream>>>(row_ptr, src_sorted, dinv, adinv,
                                                    fa, hb, beta, fb);

    out_kernel<<<(NN + 255) / 256, 256, 0, stream>>>(fb, W2, b2, out);
}

// Round 6
// 424.704 us; speedup vs baseline: 7.3192x; 1.1470x over previous
//
#include <hip/hip_runtime.h>
#include <math.h>

#define NN   100000   // nodes
#define NE   1600000  // edges
#define IND  256      // input dim
#define HIDD 64       // hidden dim
#define OUTD 40       // output dim
#define COEF 0.1f     // 2*mu/p = 2*0.1/2.0

#define PSHIFT 10
#define PSIZE  1024                       // nodes per partition == scan chunk
#define NPART  ((NN + PSIZE - 1) / PSIZE) // 98

#define CHUNK_A 4096      // edges per partition-pass block
#define PBLKS   ((NE + CHUNK_A - 1) / CHUNK_A)   // 391

typedef __attribute__((ext_vector_type(8))) short frag8;   // 8 bf16
typedef __attribute__((ext_vector_type(4))) float f32x4;

__device__ __forceinline__ unsigned short f2bf(float x) {  // RNE
    unsigned u = __float_as_uint(x);
    u += 0x7fffu + ((u >> 16) & 1u);
    return (unsigned short)(u >> 16);
}
__device__ __forceinline__ float bflo(unsigned v) { return __uint_as_float(v << 16); }
__device__ __forceinline__ float bfhi(unsigned v) { return __uint_as_float(v & 0xffff0000u); }

// ---------------------------------------------------------------- in-degree
__global__ void deg_kernel(const int* __restrict__ dst, int* __restrict__ indeg) {
    int e = blockIdx.x * blockDim.x + threadIdx.x;
    if (e < NE) atomicAdd(&indeg[dst[e]], 1);
}

// ---- per-node dinv/adinv/beta + per-partition degree sum (fused scanA)
// 98 blocks x 256 threads; block b covers nodes [b*1024, b*1024+1024)
__global__ __launch_bounds__(256) void nodeA_kernel(const int* __restrict__ indeg,
                                                    float* __restrict__ dinv,
                                                    float* __restrict__ adinv,
                                                    float* __restrict__ beta,
                                                    int* __restrict__ blocksum) {
    __shared__ int lds[256];
    int b = blockIdx.x, t = threadIdx.x;
    int s = 0;
#pragma unroll
    for (int j = 0; j < 4; j++) {
        int i = b * PSIZE + j * 256 + t;
        if (i < NN) {
            int d = indeg[i];
            s += d;
            float deg = (d > 0) ? (float)d : 1.0f;
            float di = rsqrtf(deg);
            dinv[i] = di;
            float denom = (float)d / deg + COEF;
            float a = 1.0f / denom;
            adinv[i] = a * di;
            beta[i]  = COEF * a;
        }
    }
    lds[t] = s;
    __syncthreads();
    for (int off = 128; off; off >>= 1) {
        if (t < off) lds[t] += lds[t + off];
        __syncthreads();
    }
    if (t == 0) blocksum[b] = lds[0];
}

// ---- exclusive scan of 98 partition sums -> bscan (read-only) + gcursor (mutable)
__global__ void scanB_kernel(const int* __restrict__ blocksum,
                             int* __restrict__ bscan,
                             int* __restrict__ gcursor,
                             int* __restrict__ row_ptr) {
    if (threadIdx.x == 0 && blockIdx.x == 0) {
        int acc = 0;
        for (int i = 0; i < NPART; i++) {
            bscan[i]   = acc;
            gcursor[i] = acc;
            acc += blocksum[i];
        }
        row_ptr[NN] = acc;   // == NE
    }
}

// ---- bin edges by dst>>10 into partition-ordered ep (int2{src,dst})
__global__ __launch_bounds__(256) void pfill_kernel(const int* __restrict__ src,
                                                    const int* __restrict__ dst,
                                                    int* __restrict__ gcursor,
                                                    int2* __restrict__ ep) {
    __shared__ int cnt[NPART];
    __shared__ int basep[NPART];
    int t = threadIdx.x;
    if (t < NPART) cnt[t] = 0;
    __syncthreads();
    int base = blockIdx.x * CHUNK_A;

    int v[16];
#pragma unroll
    for (int j = 0; j < 16; j++) {
        int e = base + j * 256 + t;
        v[j] = (e < NE) ? dst[e] : -1;
        if (v[j] >= 0) atomicAdd(&cnt[v[j] >> PSHIFT], 1);
    }
    __syncthreads();
    if (t < NPART) {
        basep[t] = atomicAdd(&gcursor[t], cnt[t]);
        cnt[t] = 0;
    }
    __syncthreads();
#pragma unroll
    for (int j = 0; j < 16; j++) {
        int e = base + j * 256 + t;
        if (v[j] >= 0) {
            int p = v[j] >> PSHIFT;
            int pos = basep[p] + atomicAdd(&cnt[p], 1);
            ep[pos] = make_int2(src[e], v[j]);
        }
    }
}

// ---- per-partition CSR fill: LDS node-scan (fused scanC) + LDS cursors.
// One 1024-thread block per partition; all writes land in a 65 KB window
// owned by this CU -> no cross-XCD partial-line writebacks.
__global__ __launch_bounds__(1024) void fill3_kernel(const int* __restrict__ indeg,
                                                     const int* __restrict__ bscan,
                                                     const int2* __restrict__ ep,
                                                     int* __restrict__ row_ptr,
                                                     int* __restrict__ src_sorted) {
    __shared__ int lds[PSIZE];
    __shared__ int cursor[PSIZE];
    int p = blockIdx.x, t = threadIdx.x;
    int n0 = p * PSIZE;
    int n = n0 + t;
    int d = (n < NN) ? indeg[n] : 0;
    lds[t] = d;
    __syncthreads();
    // inclusive Hillis-Steele scan over 1024 degrees
    for (int off = 1; off < PSIZE; off <<= 1) {
        int x = (t >= off) ? lds[t - off] : 0;
        __syncthreads();
        lds[t] += x;
        __syncthreads();
    }
    int ebase = bscan[p];
    int excl = lds[t] - d + ebase;
    if (n < NN) row_ptr[n] = excl;
    cursor[t] = excl;
    __syncthreads();

    int eend = (p == NPART - 1) ? NE : bscan[p + 1];
    for (int e = ebase + t; e < eend; e += PSIZE) {
        int2 sd = ep[e];
        int pos = atomicAdd(&cursor[sd.y - n0], 1);
        src_sorted[pos] = sd.x;
    }
}

// ---------------------- h = relu(x @ W1 + b1), bf16 MFMA, bf16 output
#define XPAD 136   // 128+8 shorts
#define WPAD 264   // 256+8 shorts
__global__ __launch_bounds__(256) void gemm1_kernel(const float* __restrict__ x,
                                                    const float* __restrict__ W1,
                                                    const float* __restrict__ b1,
                                                    unsigned short* __restrict__ hb) {
    __shared__ short wt[64 * WPAD];   // wt[n][k] = W1[k][n]
    __shared__ short xa[64 * XPAD];   // xa[r][k-half]
    int tid = threadIdx.x;
    int block0 = blockIdx.x * 64;

    for (int i = tid; i < IND * HIDD; i += 256) {
        int k = i >> 6, n = i & 63;
        wt[n * WPAD + k] = (short)f2bf(W1[i]);
    }

    const float4* x4 = (const float4*)(x + (size_t)block0 * IND);
    int wave = tid >> 6, lane = tid & 63;
    int m = lane & 15, q = lane >> 4;

    f32x4 acc[4] = {};

    for (int half = 0; half < 2; half++) {
        __syncthreads();
#pragma unroll
        for (int i = 0; i < 8; i++) {
            int f = i * 256 + tid;
            int row = f >> 5;
            int k4 = f & 31;
            int grow = block0 + row;
            float4 v = make_float4(0.f, 0.f, 0.f, 0.f);
            if (grow < NN) v = x4[row * 64 + half * 32 + k4];
            short4 sv;
            sv.x = (short)f2bf(v.x); sv.y = (short)f2bf(v.y);
            sv.z = (short)f2bf(v.z); sv.w = (short)f2bf(v.w);
            *(short4*)&xa[row * XPAD + k4 * 4] = sv;
        }
        __syncthreads();

        const short* arow = &xa[(wave * 16 + m) * XPAD + q * 8];
#pragma unroll
        for (int kt = 0; kt < 4; kt++) {
            frag8 a = *(const frag8*)(arow + kt * 32);
#pragma unroll
            for (int j = 0; j < 4; j++) {
                frag8 b = *(const frag8*)(&wt[(j * 16 + m) * WPAD + half * 128 + kt * 32 + q * 8]);
                acc[j] = __builtin_amdgcn_mfma_f32_16x16x32_bf16(a, b, acc[j], 0, 0, 0);
            }
        }
    }

#pragma unroll
    for (int j = 0; j < 4; j++) {
        int gcol = j * 16 + m;
        float bias = b1[gcol];
#pragma unroll
        for (int r = 0; r < 4; r++) {
            int grow = block0 + wave * 16 + q * 4 + r;
            if (grow < NN)
                hb[(size_t)grow * HIDD + gcol] = f2bf(fmaxf(acc[j][r] + bias, 0.0f));
        }
    }
}

// --- fn[i] = beta[i]*h[i] + adinv[i] * sum_e dinv[src_e] * f[src_e]  (bf16 CSR gather)
__global__ __launch_bounds__(256) void gather_kernel(const int* __restrict__ row_ptr,
                                                     const int* __restrict__ src_sorted,
                                                     const float* __restrict__ dinv,
                                                     const float* __restrict__ adinv,
                                                     const unsigned short* __restrict__ fb,
                                                     const unsigned short* __restrict__ hb,
                                                     const float* __restrict__ beta,
                                                     unsigned short* __restrict__ fnb) {
    int wid = threadIdx.x >> 6, lane = threadIdx.x & 63;
    int node = blockIdx.x * 4 + wid;
    if (node >= NN) return;
    int base = row_ptr[node];
    int end  = row_ptr[node + 1];
    int g = lane >> 3, c = lane & 7;

    float acc[8];
#pragma unroll
    for (int i = 0; i < 8; i++) acc[i] = 0.f;

    for (int e = base + g; e < end; e += 8) {
        int s   = src_sorted[e];
        float w = dinv[s];
        uint4 v = ((const uint4*)fb)[(size_t)s * 8 + c];
        acc[0] += w * bflo(v.x); acc[1] += w * bfhi(v.x);
        acc[2] += w * bflo(v.y); acc[3] += w * bfhi(v.y);
        acc[4] += w * bflo(v.z); acc[5] += w * bfhi(v.z);
        acc[6] += w * bflo(v.w); acc[7] += w * bfhi(v.w);
    }
#pragma unroll
    for (int i = 0; i < 8; i++) {
        acc[i] += __shfl_xor(acc[i], 8);
        acc[i] += __shfl_xor(acc[i], 16);
        acc[i] += __shfl_xor(acc[i], 32);
    }

    if (g == 0) {
        float an = adinv[node];
        float b  = beta[node];
        uint4 hv = ((const uint4*)hb)[(size_t)node * 8 + c];
        float o[8];
        o[0] = an * acc[0] + b * bflo(hv.x); o[1] = an * acc[1] + b * bfhi(hv.x);
        o[2] = an * acc[2] + b * bflo(hv.y); o[3] = an * acc[3] + b * bfhi(hv.y);
        o[4] = an * acc[4] + b * bflo(hv.z); o[5] = an * acc[5] + b * bfhi(hv.z);
        o[6] = an * acc[6] + b * bflo(hv.w); o[7] = an * acc[7] + b * bfhi(hv.w);
        uint4 r;
        r.x = (unsigned)f2bf(o[0]) | ((unsigned)f2bf(o[1]) << 16);
        r.y = (unsigned)f2bf(o[2]) | ((unsigned)f2bf(o[3]) << 16);
        r.z = (unsigned)f2bf(o[4]) | ((unsigned)f2bf(o[5]) << 16);
        r.w = (unsigned)f2bf(o[6]) | ((unsigned)f2bf(o[7]) << 16);
        ((uint4*)fnb)[(size_t)node * 8 + c] = r;
    }
}

// ------------------- out = log_softmax(f @ W2 + b2), bf16 MFMA
__global__ __launch_bounds__(256) void out_kernel(const unsigned short* __restrict__ fb,
                                                  const float* __restrict__ W2,
                                                  const float* __restrict__ b2,
                                                  float* __restrict__ out) {
    __shared__ float w2l[HIDD * OUTD];   // raw W2, 10 KB
    int tid = threadIdx.x;
    for (int i = tid; i < HIDD * OUTD; i += 256) w2l[i] = W2[i];
    __syncthreads();

    int wave = tid >> 6, lane = tid & 63;
    int m = lane & 15, q = lane >> 4;

    frag8 bfr[3][2];
    float bias[3];
#pragma unroll
    for (int j = 0; j < 3; j++) {
        int n = j * 16 + m;
        bias[j] = (n < OUTD) ? b2[n] : 0.0f;
#pragma unroll
        for (int s = 0; s < 2; s++) {
            short tmp[8];
#pragma unroll
            for (int i = 0; i < 8; i++) {
                int k = s * 32 + q * 8 + i;
                float w = (n < OUTD) ? w2l[k * OUTD + n] : 0.0f;
                tmp[i] = (short)f2bf(w);
            }
            bfr[j][s] = *(frag8*)tmp;
        }
    }

    int block0 = blockIdx.x * 256;
    for (int t = 0; t < 4; t++) {
        int row0 = block0 + wave * 64 + t * 16;
        if (row0 >= NN) break;
        int arow = row0 + m;
        if (arow >= NN) arow = NN - 1;
        const frag8* ap = (const frag8*)(fb + (size_t)arow * HIDD);
        frag8 a0 = ap[q];
        frag8 a1 = ap[4 + q];

        f32x4 acc[3] = {};
#pragma unroll
        for (int j = 0; j < 3; j++) {
            acc[j] = __builtin_amdgcn_mfma_f32_16x16x32_bf16(a0, bfr[j][0], acc[j], 0, 0, 0);
            acc[j] = __builtin_amdgcn_mfma_f32_16x16x32_bf16(a1, bfr[j][1], acc[j], 0, 0, 0);
        }

#pragma unroll
        for (int r = 0; r < 4; r++) {
            int orow = row0 + q * 4 + r;
            float v0 = acc[0][r] + bias[0];
            float v1 = acc[1][r] + bias[1];
            float v2 = (m < 8) ? (acc[2][r] + bias[2]) : -INFINITY;
            float mx = fmaxf(fmaxf(v0, v1), v2);
            mx = fmaxf(mx, __shfl_xor(mx, 1));
            mx = fmaxf(mx, __shfl_xor(mx, 2));
            mx = fmaxf(mx, __shfl_xor(mx, 4));
            mx = fmaxf(mx, __shfl_xor(mx, 8));
            float sum = __expf(v0 - mx) + __expf(v1 - mx) + ((m < 8) ? __expf(v2 - mx) : 0.0f);
            sum += __shfl_xor(sum, 1);
            sum += __shfl_xor(sum, 2);
            sum += __shfl_xor(sum, 4);
            sum += __shfl_xor(sum, 8);
            float ls = mx + __logf(sum);
            if (orow < NN) {
                float* orow_p = out + (size_t)orow * OUTD;
                orow_p[m]      = v0 - ls;
                orow_p[16 + m] = v1 - ls;
                if (m < 8) orow_p[32 + m] = v2 - ls;
            }
        }
    }
}

// ----------------------------------------------------------------------------
static inline size_t align256(size_t x) { return (x + 255) & ~(size_t)255; }

extern "C" void kernel_launch(void* const* d_in, const int* in_sizes, int n_in,
                              void* d_out, int out_size, void* d_ws, size_t ws_size,
                              hipStream_t stream) {
    const float* x  = (const float*)d_in[0];
    const int*   ei = (const int*)d_in[1];
    const float* W1 = (const float*)d_in[2];
    const float* b1 = (const float*)d_in[3];
    const float* W2 = (const float*)d_in[4];
    const float* b2 = (const float*)d_in[5];
    float* out = (float*)d_out;

    const int* src = ei;        // edge_index[0]
    const int* dst = ei + NE;   // edge_index[1]

    char* ws = (char*)d_ws;
    size_t off = 0;
    int*   indeg    = (int*)(ws + off);   off += align256((size_t)NN * 4);
    float* dinv     = (float*)(ws + off); off += align256((size_t)NN * 4);
    float* adinv    = (float*)(ws + off); off += align256((size_t)NN * 4);
    float* beta     = (float*)(ws + off); off += align256((size_t)NN * 4);
    int*   row_ptr  = (int*)(ws + off);   off += align256((size_t)(NN + 1) * 4);
    int*   blocksum = (int*)(ws + off);   off += align256((size_t)NPART * 4);
    int*   bscan    = (int*)(ws + off);   off += align256((size_t)NPART * 4);
    int*   gcursor  = (int*)(ws + off);   off += align256((size_t)NPART * 4);
    int*   src_sorted = (int*)(ws + off); off += align256((size_t)NE * 4);
    int2*  ep       = (int2*)(ws + off);  off += align256((size_t)NE * 8);
    unsigned short* hb = (unsigned short*)(ws + off); off += align256((size_t)NN * HIDD * 2);
    unsigned short* fa = (unsigned short*)(ws + off); off += align256((size_t)NN * HIDD * 2);
    unsigned short* fb = (unsigned short*)(ws + off); off += align256((size_t)NN * HIDD * 2);

    hipMemsetAsync(indeg, 0, (size_t)NN * 4, stream);

    deg_kernel<<<(NE + 255) / 256, 256, 0, stream>>>(dst, indeg);
    nodeA_kernel<<<NPART, 256, 0, stream>>>(indeg, dinv, adinv, beta, blocksum);
    scanB_kernel<<<1, 64, 0, stream>>>(blocksum, bscan, gcursor, row_ptr);

    pfill_kernel<<<PBLKS, 256, 0, stream>>>(src, dst, gcursor, ep);
    fill3_kernel<<<NPART, 1024, 0, stream>>>(indeg, bscan, ep, row_ptr, src_sorted);

    gemm1_kernel<<<(NN + 63) / 64, 256, 0, stream>>>(x, W1, b1, hb);

    // iteration 1: fa = beta*h + A h
    gather_kernel<<<(NN + 3) / 4, 256, 0, stream>>>(row_ptr, src_sorted, dinv, adinv,
                                                    hb, hb, beta, fa);
    // iteration 2: fb = beta*h + A fa
    gather_kernel<<<(NN + 3) / 4, 256, 0, stream>>>(row_ptr, src_sorted, dinv, adinv,
                                                    fa, hb, beta, fb);

    out_kernel<<<(NN + 255) / 256, 256, 0, stream>>>(fb, W2, b2, out);
}

// Round 7
// 419.154 us; speedup vs baseline: 7.4162x; 1.0132x over previous
//
#include <hip/hip_runtime.h>
#include <math.h>

#define NN   100000   // nodes
#define NE   1600000  // edges
#define IND  256      // input dim
#define HIDD 64       // hidden dim
#define OUTD 40       // output dim
#define COEF 0.1f     // 2*mu/p = 2*0.1/2.0

#define PSHIFT 10
#define PSIZE  1024                       // nodes per partition == scan chunk
#define NPART  ((NN + PSIZE - 1) / PSIZE) // 98

#define CHUNK_A 4096      // edges per partition-pass block
#define PBLKS   ((NE + CHUNK_A - 1) / CHUNK_A)   // 391

typedef __attribute__((ext_vector_type(8))) short frag8;   // 8 bf16
typedef __attribute__((ext_vector_type(4))) float f32x4;

__device__ __forceinline__ unsigned short f2bf(float x) {  // RNE
    unsigned u = __float_as_uint(x);
    u += 0x7fffu + ((u >> 16) & 1u);
    return (unsigned short)(u >> 16);
}
__device__ __forceinline__ float bflo(unsigned v) { return __uint_as_float(v << 16); }
__device__ __forceinline__ float bfhi(unsigned v) { return __uint_as_float(v & 0xffff0000u); }

// ---------------------------------------------------------------- in-degree
__global__ void deg_kernel(const int* __restrict__ dst, int* __restrict__ indeg) {
    int e = blockIdx.x * blockDim.x + threadIdx.x;
    if (e < NE) atomicAdd(&indeg[dst[e]], 1);
}

// ---- per-node dinv/adinv/beta + per-partition degree sum (fused scanA)
__global__ __launch_bounds__(256) void nodeA_kernel(const int* __restrict__ indeg,
                                                    float* __restrict__ dinv,
                                                    float* __restrict__ adinv,
                                                    float* __restrict__ beta,
                                                    int* __restrict__ blocksum) {
    __shared__ int lds[256];
    int b = blockIdx.x, t = threadIdx.x;
    int s = 0;
#pragma unroll
    for (int j = 0; j < 4; j++) {
        int i = b * PSIZE + j * 256 + t;
        if (i < NN) {
            int d = indeg[i];
            s += d;
            float deg = (d > 0) ? (float)d : 1.0f;
            float di = rsqrtf(deg);
            dinv[i] = di;
            float denom = (float)d / deg + COEF;
            float a = 1.0f / denom;
            adinv[i] = a * di;
            beta[i]  = COEF * a;
        }
    }
    lds[t] = s;
    __syncthreads();
    for (int off = 128; off; off >>= 1) {
        if (t < off) lds[t] += lds[t + off];
        __syncthreads();
    }
    if (t == 0) blocksum[b] = lds[0];
}

// ---- exclusive scan of 98 partition sums -> bscan (read-only) + gcursor (mutable)
__global__ void scanB_kernel(const int* __restrict__ blocksum,
                             int* __restrict__ bscan,
                             int* __restrict__ gcursor,
                             int* __restrict__ row_ptr) {
    if (threadIdx.x == 0 && blockIdx.x == 0) {
        int acc = 0;
        for (int i = 0; i < NPART; i++) {
            bscan[i]   = acc;
            gcursor[i] = acc;
            acc += blocksum[i];
        }
        row_ptr[NN] = acc;   // == NE
    }
}

// ---- bin edges by dst>>10 into partition-ordered ep (int2{src,dst})
__global__ __launch_bounds__(256) void pfill_kernel(const int* __restrict__ src,
                                                    const int* __restrict__ dst,
                                                    int* __restrict__ gcursor,
                                                    int2* __restrict__ ep) {
    __shared__ int cnt[NPART];
    __shared__ int basep[NPART];
    int t = threadIdx.x;
    if (t < NPART) cnt[t] = 0;
    __syncthreads();
    int base = blockIdx.x * CHUNK_A;

    int v[16];
#pragma unroll
    for (int j = 0; j < 16; j++) {
        int e = base + j * 256 + t;
        v[j] = (e < NE) ? dst[e] : -1;
        if (v[j] >= 0) atomicAdd(&cnt[v[j] >> PSHIFT], 1);
    }
    __syncthreads();
    if (t < NPART) {
        basep[t] = atomicAdd(&gcursor[t], cnt[t]);
        cnt[t] = 0;
    }
    __syncthreads();
#pragma unroll
    for (int j = 0; j < 16; j++) {
        int e = base + j * 256 + t;
        if (v[j] >= 0) {
            int p = v[j] >> PSHIFT;
            int pos = basep[p] + atomicAdd(&cnt[p], 1);
            ep[pos] = make_int2(src[e], v[j]);
        }
    }
}

// ---- per-partition CSR fill: LDS node-scan + LDS cursors, window owned by 1 CU
__global__ __launch_bounds__(1024) void fill3_kernel(const int* __restrict__ indeg,
                                                     const int* __restrict__ bscan,
                                                     const int2* __restrict__ ep,
                                                     int* __restrict__ row_ptr,
                                                     int* __restrict__ src_sorted) {
    __shared__ int lds[PSIZE];
    __shared__ int cursor[PSIZE];
    int p = blockIdx.x, t = threadIdx.x;
    int n0 = p * PSIZE;
    int n = n0 + t;
    int d = (n < NN) ? indeg[n] : 0;
    lds[t] = d;
    __syncthreads();
    for (int off = 1; off < PSIZE; off <<= 1) {
        int x = (t >= off) ? lds[t - off] : 0;
        __syncthreads();
        lds[t] += x;
        __syncthreads();
    }
    int ebase = bscan[p];
    int excl = lds[t] - d + ebase;
    if (n < NN) row_ptr[n] = excl;
    cursor[t] = excl;
    __syncthreads();

    int eend = (p == NPART - 1) ? NE : bscan[p + 1];
    for (int e = ebase + t; e < eend; e += PSIZE) {
        int2 sd = ep[e];
        int pos = atomicAdd(&cursor[sd.y - n0], 1);
        src_sorted[pos] = sd.x;
    }
}

// ---- one-shot: w1t[n][k] = bf16(W1[k][n])  (32 KB, L1-resident thereafter)
__global__ void w1t_kernel(const float* __restrict__ W1,
                           unsigned short* __restrict__ w1t) {
    int i = blockIdx.x * blockDim.x + threadIdx.x;
    if (i >= IND * HIDD) return;
    int k = i >> 6, n = i & 63;
    w1t[n * IND + k] = f2bf(W1[i]);
}

// ---------------------- h = relu(x @ W1 + b1), bf16 MFMA, LDS-free
// Block = 256 threads (4 waves), each wave owns 16 rows. A loaded straight
// from global x (fp32) and converted in-register; B-fragments from w1t
// (bf16, 32 KB -> L1-hit). No __shared__, no __syncthreads.
__global__ __launch_bounds__(256) void gemm1_kernel(const float* __restrict__ x,
                                                    const unsigned short* __restrict__ w1t,
                                                    const float* __restrict__ b1,
                                                    unsigned short* __restrict__ hb) {
    int tid = threadIdx.x;
    int wave = tid >> 6, lane = tid & 63;
    int m = lane & 15, q = lane >> 4;

    int row0 = blockIdx.x * 64 + wave * 16;
    int arow = row0 + m;
    if (arow >= NN) arow = NN - 1;          // clamp; masked at store
    const float* xr = x + (size_t)arow * IND;

    f32x4 acc[4] = {};

#pragma unroll 2
    for (int ks = 0; ks < 8; ks++) {
        float4 xv0 = *(const float4*)(xr + ks * 32 + q * 8);
        float4 xv1 = *(const float4*)(xr + ks * 32 + q * 8 + 4);
        short tmp[8];
        tmp[0] = (short)f2bf(xv0.x); tmp[1] = (short)f2bf(xv0.y);
        tmp[2] = (short)f2bf(xv0.z); tmp[3] = (short)f2bf(xv0.w);
        tmp[4] = (short)f2bf(xv1.x); tmp[5] = (short)f2bf(xv1.y);
        tmp[6] = (short)f2bf(xv1.z); tmp[7] = (short)f2bf(xv1.w);
        frag8 a = *(frag8*)tmp;
#pragma unroll
        for (int j = 0; j < 4; j++) {
            frag8 b = *(const frag8*)(w1t + (j * 16 + m) * IND + ks * 32 + q * 8);
            acc[j] = __builtin_amdgcn_mfma_f32_16x16x32_bf16(a, b, acc[j], 0, 0, 0);
        }
    }

#pragma unroll
    for (int j = 0; j < 4; j++) {
        int gcol = j * 16 + m;
        float bias = b1[gcol];
#pragma unroll
        for (int r = 0; r < 4; r++) {
            int grow = row0 + q * 4 + r;
            if (grow < NN)
                hb[(size_t)grow * HIDD + gcol] = f2bf(fmaxf(acc[j][r] + bias, 0.0f));
        }
    }
}

// --- fn[i] = beta[i]*h[i] + adinv[i] * sum_e dinv[src_e] * f[src_e]  (bf16 CSR gather)
__global__ __launch_bounds__(256) void gather_kernel(const int* __restrict__ row_ptr,
                                                     const int* __restrict__ src_sorted,
                                                     const float* __restrict__ dinv,
                                                     const float* __restrict__ adinv,
                                                     const unsigned short* __restrict__ fb,
                                                     const unsigned short* __restrict__ hb,
                                                     const float* __restrict__ beta,
                                                     unsigned short* __restrict__ fnb) {
    int wid = threadIdx.x >> 6, lane = threadIdx.x & 63;
    int node = blockIdx.x * 4 + wid;
    if (node >= NN) return;
    int base = row_ptr[node];
    int end  = row_ptr[node + 1];
    int g = lane >> 3, c = lane & 7;

    float acc[8];
#pragma unroll
    for (int i = 0; i < 8; i++) acc[i] = 0.f;

    for (int e = base + g; e < end; e += 8) {
        int s   = src_sorted[e];
        float w = dinv[s];
        uint4 v = ((const uint4*)fb)[(size_t)s * 8 + c];
        acc[0] += w * bflo(v.x); acc[1] += w * bfhi(v.x);
        acc[2] += w * bflo(v.y); acc[3] += w * bfhi(v.y);
        acc[4] += w * bflo(v.z); acc[5] += w * bfhi(v.z);
        acc[6] += w * bflo(v.w); acc[7] += w * bfhi(v.w);
    }
#pragma unroll
    for (int i = 0; i < 8; i++) {
        acc[i] += __shfl_xor(acc[i], 8);
        acc[i] += __shfl_xor(acc[i], 16);
        acc[i] += __shfl_xor(acc[i], 32);
    }

    if (g == 0) {
        float an = adinv[node];
        float b  = beta[node];
        uint4 hv = ((const uint4*)hb)[(size_t)node * 8 + c];
        float o[8];
        o[0] = an * acc[0] + b * bflo(hv.x); o[1] = an * acc[1] + b * bfhi(hv.x);
        o[2] = an * acc[2] + b * bflo(hv.y); o[3] = an * acc[3] + b * bfhi(hv.y);
        o[4] = an * acc[4] + b * bflo(hv.z); o[5] = an * acc[5] + b * bfhi(hv.z);
        o[6] = an * acc[6] + b * bflo(hv.w); o[7] = an * acc[7] + b * bfhi(hv.w);
        uint4 r;
        r.x = (unsigned)f2bf(o[0]) | ((unsigned)f2bf(o[1]) << 16);
        r.y = (unsigned)f2bf(o[2]) | ((unsigned)f2bf(o[3]) << 16);
        r.z = (unsigned)f2bf(o[4]) | ((unsigned)f2bf(o[5]) << 16);
        r.w = (unsigned)f2bf(o[6]) | ((unsigned)f2bf(o[7]) << 16);
        ((uint4*)fnb)[(size_t)node * 8 + c] = r;
    }
}

// ------------------- out = log_softmax(f @ W2 + b2), bf16 MFMA
__global__ __launch_bounds__(256) void out_kernel(const unsigned short* __restrict__ fb,
                                                  const float* __restrict__ W2,
                                                  const float* __restrict__ b2,
                                                  float* __restrict__ out) {
    __shared__ float w2l[HIDD * OUTD];   // raw W2, 10 KB
    int tid = threadIdx.x;
    for (int i = tid; i < HIDD * OUTD; i += 256) w2l[i] = W2[i];
    __syncthreads();

    int wave = tid >> 6, lane = tid & 63;
    int m = lane & 15, q = lane >> 4;

    frag8 bfr[3][2];
    float bias[3];
#pragma unroll
    for (int j = 0; j < 3; j++) {
        int n = j * 16 + m;
        bias[j] = (n < OUTD) ? b2[n] : 0.0f;
#pragma unroll
        for (int s = 0; s < 2; s++) {
            short tmp[8];
#pragma unroll
            for (int i = 0; i < 8; i++) {
                int k = s * 32 + q * 8 + i;
                float w = (n < OUTD) ? w2l[k * OUTD + n] : 0.0f;
                tmp[i] = (short)f2bf(w);
            }
            bfr[j][s] = *(frag8*)tmp;
        }
    }

    int block0 = blockIdx.x * 256;
    for (int t = 0; t < 4; t++) {
        int row0 = block0 + wave * 64 + t * 16;
        if (row0 >= NN) break;
        int arow = row0 + m;
        if (arow >= NN) arow = NN - 1;
        const frag8* ap = (const frag8*)(fb + (size_t)arow * HIDD);
        frag8 a0 = ap[q];
        frag8 a1 = ap[4 + q];

        f32x4 acc[3] = {};
#pragma unroll
        for (int j = 0; j < 3; j++) {
            acc[j] = __builtin_amdgcn_mfma_f32_16x16x32_bf16(a0, bfr[j][0], acc[j], 0, 0, 0);
            acc[j] = __builtin_amdgcn_mfma_f32_16x16x32_bf16(a1, bfr[j][1], acc[j], 0, 0, 0);
        }

#pragma unroll
        for (int r = 0; r < 4; r++) {
            int orow = row0 + q * 4 + r;
            float v0 = acc[0][r] + bias[0];
            float v1 = acc[1][r] + bias[1];
            float v2 = (m < 8) ? (acc[2][r] + bias[2]) : -INFINITY;
            float mx = fmaxf(fmaxf(v0, v1), v2);
            mx = fmaxf(mx, __shfl_xor(mx, 1));
            mx = fmaxf(mx, __shfl_xor(mx, 2));
            mx = fmaxf(mx, __shfl_xor(mx, 4));
            mx = fmaxf(mx, __shfl_xor(mx, 8));
            float sum = __expf(v0 - mx) + __expf(v1 - mx) + ((m < 8) ? __expf(v2 - mx) : 0.0f);
            sum += __shfl_xor(sum, 1);
            sum += __shfl_xor(sum, 2);
            sum += __shfl_xor(sum, 4);
            sum += __shfl_xor(sum, 8);
            float ls = mx + __logf(sum);
            if (orow < NN) {
                float* orow_p = out + (size_t)orow * OUTD;
                orow_p[m]      = v0 - ls;
                orow_p[16 + m] = v1 - ls;
                if (m < 8) orow_p[32 + m] = v2 - ls;
            }
        }
    }
}

// ----------------------------------------------------------------------------
static inline size_t align256(size_t x) { return (x + 255) & ~(size_t)255; }

extern "C" void kernel_launch(void* const* d_in, const int* in_sizes, int n_in,
                              void* d_out, int out_size, void* d_ws, size_t ws_size,
                              hipStream_t stream) {
    const float* x  = (const float*)d_in[0];
    const int*   ei = (const int*)d_in[1];
    const float* W1 = (const float*)d_in[2];
    const float* b1 = (const float*)d_in[3];
    const float* W2 = (const float*)d_in[4];
    const float* b2 = (const float*)d_in[5];
    float* out = (float*)d_out;

    const int* src = ei;        // edge_index[0]
    const int* dst = ei + NE;   // edge_index[1]

    char* ws = (char*)d_ws;
    size_t off = 0;
    int*   indeg    = (int*)(ws + off);   off += align256((size_t)NN * 4);
    float* dinv     = (float*)(ws + off); off += align256((size_t)NN * 4);
    float* adinv    = (float*)(ws + off); off += align256((size_t)NN * 4);
    float* beta     = (float*)(ws + off); off += align256((size_t)NN * 4);
    int*   row_ptr  = (int*)(ws + off);   off += align256((size_t)(NN + 1) * 4);
    int*   blocksum = (int*)(ws + off);   off += align256((size_t)NPART * 4);
    int*   bscan    = (int*)(ws + off);   off += align256((size_t)NPART * 4);
    int*   gcursor  = (int*)(ws + off);   off += align256((size_t)NPART * 4);
    int*   src_sorted = (int*)(ws + off); off += align256((size_t)NE * 4);
    int2*  ep       = (int2*)(ws + off);  off += align256((size_t)NE * 8);
    unsigned short* w1t = (unsigned short*)(ws + off); off += align256((size_t)IND * HIDD * 2);
    unsigned short* hb = (unsigned short*)(ws + off); off += align256((size_t)NN * HIDD * 2);
    unsigned short* fa = (unsigned short*)(ws + off); off += align256((size_t)NN * HIDD * 2);
    unsigned short* fb = (unsigned short*)(ws + off); off += align256((size_t)NN * HIDD * 2);

    hipMemsetAsync(indeg, 0, (size_t)NN * 4, stream);

    deg_kernel<<<(NE + 255) / 256, 256, 0, stream>>>(dst, indeg);
    nodeA_kernel<<<NPART, 256, 0, stream>>>(indeg, dinv, adinv, beta, blocksum);
    scanB_kernel<<<1, 64, 0, stream>>>(blocksum, bscan, gcursor, row_ptr);

    pfill_kernel<<<PBLKS, 256, 0, stream>>>(src, dst, gcursor, ep);
    fill3_kernel<<<NPART, 1024, 0, stream>>>(indeg, bscan, ep, row_ptr, src_sorted);

    w1t_kernel<<<(IND * HIDD + 255) / 256, 256, 0, stream>>>(W1, w1t);
    gemm1_kernel<<<(NN + 63) / 64, 256, 0, stream>>>(x, w1t, b1, hb);

    // iteration 1: fa = beta*h + A h
    gather_kernel<<<(NN + 3) / 4, 256, 0, stream>>>(row_ptr, src_sorted, dinv, adinv,
                                                    hb, hb, beta, fa);
    // iteration 2: fb = beta*h + A fa
    gather_kernel<<<(NN + 3) / 4, 256, 0, stream>>>(row_ptr, src_sorted, dinv, adinv,
                                                    fa, hb, beta, fb);

    out_kernel<<<(NN + 255) / 256, 256, 0, stream>>>(fb, W2, b2, out);
}

// Round 8
// 366.383 us; speedup vs baseline: 8.4843x; 1.1440x over previous
//
#include <hip/hip_runtime.h>
#include <math.h>

#define NN   100000   // nodes
#define NE   1600000  // edges
#define IND  256      // input dim
#define HIDD 64       // hidden dim
#define OUTD 40       // output dim
#define COEF 0.1f     // 2*mu/p = 2*0.1/2.0

#define PSHIFT 10
#define PSIZE  1024                       // nodes per partition
#define NPART  ((NN + PSIZE - 1) / PSIZE) // 98

#define CHUNK_A 4096      // edges per partition-pass block
#define PBLKS   ((NE + CHUNK_A - 1) / CHUNK_A)   // 391

typedef __attribute__((ext_vector_type(8))) short frag8;   // 8 bf16
typedef __attribute__((ext_vector_type(4))) float f32x4;

__device__ __forceinline__ unsigned short f2bf(float x) {  // RNE
    unsigned u = __float_as_uint(x);
    u += 0x7fffu + ((u >> 16) & 1u);
    return (unsigned short)(u >> 16);
}
__device__ __forceinline__ float bflo(unsigned v) { return __uint_as_float(v << 16); }
__device__ __forceinline__ float bfhi(unsigned v) { return __uint_as_float(v & 0xffff0000u); }

// ---- per-partition edge counts: LDS histogram, 98 global adds per block
__global__ __launch_bounds__(256) void pcount_kernel(const int* __restrict__ dst,
                                                     int* __restrict__ gcount) {
    __shared__ int cnt[NPART];
    int t = threadIdx.x;
    if (t < NPART) cnt[t] = 0;
    __syncthreads();
    int base = blockIdx.x * CHUNK_A;
#pragma unroll
    for (int j = 0; j < 16; j++) {
        int e = base + j * 256 + t;
        if (e < NE) atomicAdd(&cnt[dst[e] >> PSHIFT], 1);
    }
    __syncthreads();
    if (t < NPART) atomicAdd(&gcount[t], cnt[t]);
}

// ---- exclusive scan of 98 partition sums -> bscan (read-only) + gcursor (mutable)
__global__ void pscan_kernel(const int* __restrict__ gcount,
                             int* __restrict__ bscan,
                             int* __restrict__ gcursor,
                             int* __restrict__ row_ptr) {
    if (threadIdx.x == 0 && blockIdx.x == 0) {
        int acc = 0;
        for (int i = 0; i < NPART; i++) {
            bscan[i]   = acc;
            gcursor[i] = acc;
            acc += gcount[i];
        }
        row_ptr[NN] = acc;   // == NE
    }
}

// ---- bin edges by dst>>10 into partition-ordered ep (int2{src,dst})
__global__ __launch_bounds__(256) void pfill_kernel(const int* __restrict__ src,
                                                    const int* __restrict__ dst,
                                                    int* __restrict__ gcursor,
                                                    int2* __restrict__ ep) {
    __shared__ int cnt[NPART];
    __shared__ int basep[NPART];
    int t = threadIdx.x;
    if (t < NPART) cnt[t] = 0;
    __syncthreads();
    int base = blockIdx.x * CHUNK_A;

    int v[16];
#pragma unroll
    for (int j = 0; j < 16; j++) {
        int e = base + j * 256 + t;
        v[j] = (e < NE) ? dst[e] : -1;
        if (v[j] >= 0) atomicAdd(&cnt[v[j] >> PSHIFT], 1);
    }
    __syncthreads();
    if (t < NPART) {
        basep[t] = atomicAdd(&gcursor[t], cnt[t]);
        cnt[t] = 0;
    }
    __syncthreads();
#pragma unroll
    for (int j = 0; j < 16; j++) {
        int e = base + j * 256 + t;
        if (v[j] >= 0) {
            int p = v[j] >> PSHIFT;
            int pos = basep[p] + atomicAdd(&cnt[p], 1);
            ep[pos] = make_int2(src[e], v[j]);
        }
    }
}

// ---- per-partition: LDS degree histogram (replaces global deg_kernel),
// node quantities (fused nodeA), LDS scan -> row_ptr, LDS-cursor scatter.
// One 1024-thread block per partition; all global writes dense & CU-owned.
__global__ __launch_bounds__(1024) void fill3_kernel(const int* __restrict__ bscan,
                                                     const int2* __restrict__ ep,
                                                     int* __restrict__ row_ptr,
                                                     int* __restrict__ src_sorted,
                                                     float* __restrict__ dinv,
                                                     float* __restrict__ adinv,
                                                     float* __restrict__ beta) {
    __shared__ int cnt[PSIZE];
    __shared__ int scan[PSIZE];
    __shared__ int cursor[PSIZE];
    int p = blockIdx.x, t = threadIdx.x;
    int n0 = p * PSIZE;
    int n = n0 + t;

    cnt[t] = 0;
    __syncthreads();
    int ebase = bscan[p];
    int eend  = (p == NPART - 1) ? NE : bscan[p + 1];
    for (int e = ebase + t; e < eend; e += PSIZE)
        atomicAdd(&cnt[ep[e].y - n0], 1);
    __syncthreads();

    int d = cnt[t];
    if (n < NN) {
        float deg = (d > 0) ? (float)d : 1.0f;
        float di = rsqrtf(deg);
        dinv[n] = di;
        float denom = (float)d / deg + COEF;
        float a = 1.0f / denom;
        adinv[n] = a * di;
        beta[n]  = COEF * a;
    }

    scan[t] = d;
    __syncthreads();
    for (int off = 1; off < PSIZE; off <<= 1) {
        int x = (t >= off) ? scan[t - off] : 0;
        __syncthreads();
        scan[t] += x;
        __syncthreads();
    }
    int excl = scan[t] - d + ebase;
    if (n < NN) row_ptr[n] = excl;
    cursor[t] = excl;
    __syncthreads();

    for (int e = ebase + t; e < eend; e += PSIZE) {
        int2 sd = ep[e];
        int pos = atomicAdd(&cursor[sd.y - n0], 1);
        src_sorted[pos] = sd.x;
    }
}

// ---- one-shot: w1t[n][k] = bf16(W1[k][n])  (32 KB, L1-resident thereafter)
__global__ void w1t_kernel(const float* __restrict__ W1,
                           unsigned short* __restrict__ w1t) {
    int i = blockIdx.x * blockDim.x + threadIdx.x;
    if (i >= IND * HIDD) return;
    int k = i >> 6, n = i & 63;
    w1t[n * IND + k] = f2bf(W1[i]);
}

// ---------------------- h = relu(x @ W1 + b1), bf16 MFMA, LDS-free
__global__ __launch_bounds__(256) void gemm1_kernel(const float* __restrict__ x,
                                                    const unsigned short* __restrict__ w1t,
                                                    const float* __restrict__ b1,
                                                    unsigned short* __restrict__ hb) {
    int tid = threadIdx.x;
    int wave = tid >> 6, lane = tid & 63;
    int m = lane & 15, q = lane >> 4;

    int row0 = blockIdx.x * 64 + wave * 16;
    int arow = row0 + m;
    if (arow >= NN) arow = NN - 1;          // clamp; masked at store
    const float* xr = x + (size_t)arow * IND;

    f32x4 acc[4] = {};

#pragma unroll 2
    for (int ks = 0; ks < 8; ks++) {
        float4 xv0 = *(const float4*)(xr + ks * 32 + q * 8);
        float4 xv1 = *(const float4*)(xr + ks * 32 + q * 8 + 4);
        short tmp[8];
        tmp[0] = (short)f2bf(xv0.x); tmp[1] = (short)f2bf(xv0.y);
        tmp[2] = (short)f2bf(xv0.z); tmp[3] = (short)f2bf(xv0.w);
        tmp[4] = (short)f2bf(xv1.x); tmp[5] = (short)f2bf(xv1.y);
        tmp[6] = (short)f2bf(xv1.z); tmp[7] = (short)f2bf(xv1.w);
        frag8 a = *(frag8*)tmp;
#pragma unroll
        for (int j = 0; j < 4; j++) {
            frag8 b = *(const frag8*)(w1t + (j * 16 + m) * IND + ks * 32 + q * 8);
            acc[j] = __builtin_amdgcn_mfma_f32_16x16x32_bf16(a, b, acc[j], 0, 0, 0);
        }
    }

#pragma unroll
    for (int j = 0; j < 4; j++) {
        int gcol = j * 16 + m;
        float bias = b1[gcol];
#pragma unroll
        for (int r = 0; r < 4; r++) {
            int grow = row0 + q * 4 + r;
            if (grow < NN)
                hb[(size_t)grow * HIDD + gcol] = f2bf(fmaxf(acc[j][r] + bias, 0.0f));
        }
    }
}

// --- fn[i] = beta[i]*h[i] + adinv[i] * sum_e dinv[src_e] * f[src_e]  (bf16 CSR gather)
__global__ __launch_bounds__(256) void gather_kernel(const int* __restrict__ row_ptr,
                                                     const int* __restrict__ src_sorted,
                                                     const float* __restrict__ dinv,
                                                     const float* __restrict__ adinv,
                                                     const unsigned short* __restrict__ fb,
                                                     const unsigned short* __restrict__ hb,
                                                     const float* __restrict__ beta,
                                                     unsigned short* __restrict__ fnb) {
    int wid = threadIdx.x >> 6, lane = threadIdx.x & 63;
    int node = blockIdx.x * 4 + wid;
    if (node >= NN) return;
    int base = row_ptr[node];
    int end  = row_ptr[node + 1];
    int g = lane >> 3, c = lane & 7;

    float acc[8];
#pragma unroll
    for (int i = 0; i < 8; i++) acc[i] = 0.f;

    for (int e = base + g; e < end; e += 8) {
        int s   = src_sorted[e];
        float w = dinv[s];
        uint4 v = ((const uint4*)fb)[(size_t)s * 8 + c];
        acc[0] += w * bflo(v.x); acc[1] += w * bfhi(v.x);
        acc[2] += w * bflo(v.y); acc[3] += w * bfhi(v.y);
        acc[4] += w * bflo(v.z); acc[5] += w * bfhi(v.z);
        acc[6] += w * bflo(v.w); acc[7] += w * bfhi(v.w);
    }
#pragma unroll
    for (int i = 0; i < 8; i++) {
        acc[i] += __shfl_xor(acc[i], 8);
        acc[i] += __shfl_xor(acc[i], 16);
        acc[i] += __shfl_xor(acc[i], 32);
    }

    if (g == 0) {
        float an = adinv[node];
        float b  = beta[node];
        uint4 hv = ((const uint4*)hb)[(size_t)node * 8 + c];
        float o[8];
        o[0] = an * acc[0] + b * bflo(hv.x); o[1] = an * acc[1] + b * bfhi(hv.x);
        o[2] = an * acc[2] + b * bflo(hv.y); o[3] = an * acc[3] + b * bfhi(hv.y);
        o[4] = an * acc[4] + b * bflo(hv.z); o[5] = an * acc[5] + b * bfhi(hv.z);
        o[6] = an * acc[6] + b * bflo(hv.w); o[7] = an * acc[7] + b * bfhi(hv.w);
        uint4 r;
        r.x = (unsigned)f2bf(o[0]) | ((unsigned)f2bf(o[1]) << 16);
        r.y = (unsigned)f2bf(o[2]) | ((unsigned)f2bf(o[3]) << 16);
        r.z = (unsigned)f2bf(o[4]) | ((unsigned)f2bf(o[5]) << 16);
        r.w = (unsigned)f2bf(o[6]) | ((unsigned)f2bf(o[7]) << 16);
        ((uint4*)fnb)[(size_t)node * 8 + c] = r;
    }
}

// ------------------- out = log_softmax(f @ W2 + b2), bf16 MFMA
__global__ __launch_bounds__(256) void out_kernel(const unsigned short* __restrict__ fb,
                                                  const float* __restrict__ W2,
                                                  const float* __restrict__ b2,
                                                  float* __restrict__ out) {
    __shared__ float w2l[HIDD * OUTD];   // raw W2, 10 KB
    int tid = threadIdx.x;
    for (int i = tid; i < HIDD * OUTD; i += 256) w2l[i] = W2[i];
    __syncthreads();

    int wave = tid >> 6, lane = tid & 63;
    int m = lane & 15, q = lane >> 4;

    frag8 bfr[3][2];
    float bias[3];
#pragma unroll
    for (int j = 0; j < 3; j++) {
        int n = j * 16 + m;
        bias[j] = (n < OUTD) ? b2[n] : 0.0f;
#pragma unroll
        for (int s = 0; s < 2; s++) {
            short tmp[8];
#pragma unroll
            for (int i = 0; i < 8; i++) {
                int k = s * 32 + q * 8 + i;
                float w = (n < OUTD) ? w2l[k * OUTD + n] : 0.0f;
                tmp[i] = (short)f2bf(w);
            }
            bfr[j][s] = *(frag8*)tmp;
        }
    }

    int block0 = blockIdx.x * 256;
    for (int t = 0; t < 4; t++) {
        int row0 = block0 + wave * 64 + t * 16;
        if (row0 >= NN) break;
        int arow = row0 + m;
        if (arow >= NN) arow = NN - 1;
        const frag8* ap = (const frag8*)(fb + (size_t)arow * HIDD);
        frag8 a0 = ap[q];
        frag8 a1 = ap[4 + q];

        f32x4 acc[3] = {};
#pragma unroll
        for (int j = 0; j < 3; j++) {
            acc[j] = __builtin_amdgcn_mfma_f32_16x16x32_bf16(a0, bfr[j][0], acc[j], 0, 0, 0);
            acc[j] = __builtin_amdgcn_mfma_f32_16x16x32_bf16(a1, bfr[j][1], acc[j], 0, 0, 0);
        }

#pragma unroll
        for (int r = 0; r < 4; r++) {
            int orow = row0 + q * 4 + r;
            float v0 = acc[0][r] + bias[0];
            float v1 = acc[1][r] + bias[1];
            float v2 = (m < 8) ? (acc[2][r] + bias[2]) : -INFINITY;
            float mx = fmaxf(fmaxf(v0, v1), v2);
            mx = fmaxf(mx, __shfl_xor(mx, 1));
            mx = fmaxf(mx, __shfl_xor(mx, 2));
            mx = fmaxf(mx, __shfl_xor(mx, 4));
            mx = fmaxf(mx, __shfl_xor(mx, 8));
            float sum = __expf(v0 - mx) + __expf(v1 - mx) + ((m < 8) ? __expf(v2 - mx) : 0.0f);
            sum += __shfl_xor(sum, 1);
            sum += __shfl_xor(sum, 2);
            sum += __shfl_xor(sum, 4);
            sum += __shfl_xor(sum, 8);
            float ls = mx + __logf(sum);
            if (orow < NN) {
                float* orow_p = out + (size_t)orow * OUTD;
                orow_p[m]      = v0 - ls;
                orow_p[16 + m] = v1 - ls;
                if (m < 8) orow_p[32 + m] = v2 - ls;
            }
        }
    }
}

// ----------------------------------------------------------------------------
static inline size_t align256(size_t x) { return (x + 255) & ~(size_t)255; }

extern "C" void kernel_launch(void* const* d_in, const int* in_sizes, int n_in,
                              void* d_out, int out_size, void* d_ws, size_t ws_size,
                              hipStream_t stream) {
    const float* x  = (const float*)d_in[0];
    const int*   ei = (const int*)d_in[1];
    const float* W1 = (const float*)d_in[2];
    const float* b1 = (const float*)d_in[3];
    const float* W2 = (const float*)d_in[4];
    const float* b2 = (const float*)d_in[5];
    float* out = (float*)d_out;

    const int* src = ei;        // edge_index[0]
    const int* dst = ei + NE;   // edge_index[1]

    char* ws = (char*)d_ws;
    size_t off = 0;
    float* dinv     = (float*)(ws + off); off += align256((size_t)NN * 4);
    float* adinv    = (float*)(ws + off); off += align256((size_t)NN * 4);
    float* beta     = (float*)(ws + off); off += align256((size_t)NN * 4);
    int*   row_ptr  = (int*)(ws + off);   off += align256((size_t)(NN + 1) * 4);
    int*   gcount   = (int*)(ws + off);   off += align256((size_t)NPART * 4);
    int*   bscan    = (int*)(ws + off);   off += align256((size_t)NPART * 4);
    int*   gcursor  = (int*)(ws + off);   off += align256((size_t)NPART * 4);
    int*   src_sorted = (int*)(ws + off); off += align256((size_t)NE * 4);
    int2*  ep       = (int2*)(ws + off);  off += align256((size_t)NE * 8);
    unsigned short* w1t = (unsigned short*)(ws + off); off += align256((size_t)IND * HIDD * 2);
    unsigned short* hb = (unsigned short*)(ws + off); off += align256((size_t)NN * HIDD * 2);
    unsigned short* fa = (unsigned short*)(ws + off); off += align256((size_t)NN * HIDD * 2);
    unsigned short* fb = (unsigned short*)(ws + off); off += align256((size_t)NN * HIDD * 2);

    hipMemsetAsync(gcount, 0, (size_t)NPART * 4, stream);

    pcount_kernel<<<PBLKS, 256, 0, stream>>>(dst, gcount);
    pscan_kernel<<<1, 64, 0, stream>>>(gcount, bscan, gcursor, row_ptr);
    pfill_kernel<<<PBLKS, 256, 0, stream>>>(src, dst, gcursor, ep);
    fill3_kernel<<<NPART, 1024, 0, stream>>>(bscan, ep, row_ptr, src_sorted,
                                             dinv, adinv, beta);

    w1t_kernel<<<(IND * HIDD + 255) / 256, 256, 0, stream>>>(W1, w1t);
    gemm1_kernel<<<(NN + 63) / 64, 256, 0, stream>>>(x, w1t, b1, hb);

    // iteration 1: fa = beta*h + A h
    gather_kernel<<<(NN + 3) / 4, 256, 0, stream>>>(row_ptr, src_sorted, dinv, adinv,
                                                    hb, hb, beta, fa);
    // iteration 2: fb = beta*h + A fa
    gather_kernel<<<(NN + 3) / 4, 256, 0, stream>>>(row_ptr, src_sorted, dinv, adinv,
                                                    fa, hb, beta, fb);

    out_kernel<<<(NN + 255) / 256, 256, 0, stream>>>(fb, W2, b2, out);
}